// Round 1
// baseline (13147.212 us; speedup 1.0000x reference)
//
#include <hip/hip_runtime.h>
#include <cstddef>
#include <cstdint>
#include <math.h>

#define EPSF 1e-8f

// Model dims (fixed)
// T=64, B=128, D=300, H=300, L=20, AH=300, N2=2B=256
// ctx gates: (T,256,1200)  agg gates: (T,128,1200) x2

// ---------------------------------------------------------------------------
// Generic NT GEMM body: C[m,n] = (bias?bias[n]:0) + (Cin?Cin[m,n]:0) + sum_k A[m,k]*B[n,k]
// A: (M,K) rm, B: (N,K) rm. 64x64 tile, 256 threads, 4x4 microtile, KT=16.
// ---------------------------------------------------------------------------
__device__ __forceinline__ void gemm_nt_body(
    const float* __restrict__ A, const float* __restrict__ B,
    const float* __restrict__ bias, const float* __restrict__ Cin,
    float* __restrict__ C, int M, int N, int K,
    float* As, float* Bs)
{
  const int tid = threadIdx.x;
  const int tx = tid & 15, ty = tid >> 4;
  const int mbase = blockIdx.y << 6, nbase = blockIdx.x << 6;
  const int lm = tid >> 2;          // 0..63
  const int lk = (tid & 3) << 2;    // 0,4,8,12
  float acc[4][4];
#pragma unroll
  for (int i = 0; i < 4; i++)
#pragma unroll
    for (int j = 0; j < 4; j++) acc[i][j] = 0.f;

  for (int kk = 0; kk < K; kk += 16) {
    // stage A tile
    {
      int m = mbase + lm;
      int kbase = kk + lk;
      float4 v = make_float4(0.f, 0.f, 0.f, 0.f);
      if (m < M) {
        if (kbase + 4 <= K) {
          v = *(const float4*)(A + (size_t)m * K + kbase);
        } else {
          const float* src = A + (size_t)m * K;
          float t0 = (kbase + 0 < K) ? src[kbase + 0] : 0.f;
          float t1 = (kbase + 1 < K) ? src[kbase + 1] : 0.f;
          float t2 = (kbase + 2 < K) ? src[kbase + 2] : 0.f;
          float t3 = (kbase + 3 < K) ? src[kbase + 3] : 0.f;
          v = make_float4(t0, t1, t2, t3);
        }
      }
      As[(lk + 0) * 64 + lm] = v.x;
      As[(lk + 1) * 64 + lm] = v.y;
      As[(lk + 2) * 64 + lm] = v.z;
      As[(lk + 3) * 64 + lm] = v.w;
    }
    // stage B tile
    {
      int n = nbase + lm;
      int kbase = kk + lk;
      float4 v = make_float4(0.f, 0.f, 0.f, 0.f);
      if (n < N) {
        if (kbase + 4 <= K) {
          v = *(const float4*)(B + (size_t)n * K + kbase);
        } else {
          const float* src = B + (size_t)n * K;
          float t0 = (kbase + 0 < K) ? src[kbase + 0] : 0.f;
          float t1 = (kbase + 1 < K) ? src[kbase + 1] : 0.f;
          float t2 = (kbase + 2 < K) ? src[kbase + 2] : 0.f;
          float t3 = (kbase + 3 < K) ? src[kbase + 3] : 0.f;
          v = make_float4(t0, t1, t2, t3);
        }
      }
      Bs[(lk + 0) * 64 + lm] = v.x;
      Bs[(lk + 1) * 64 + lm] = v.y;
      Bs[(lk + 2) * 64 + lm] = v.z;
      Bs[(lk + 3) * 64 + lm] = v.w;
    }
    __syncthreads();
#pragma unroll
    for (int k = 0; k < 16; k++) {
      float4 av = *(const float4*)(As + k * 64 + (ty << 2));
      float4 bv = *(const float4*)(Bs + k * 64 + (tx << 2));
      acc[0][0] += av.x * bv.x; acc[0][1] += av.x * bv.y; acc[0][2] += av.x * bv.z; acc[0][3] += av.x * bv.w;
      acc[1][0] += av.y * bv.x; acc[1][1] += av.y * bv.y; acc[1][2] += av.y * bv.z; acc[1][3] += av.y * bv.w;
      acc[2][0] += av.z * bv.x; acc[2][1] += av.z * bv.y; acc[2][2] += av.z * bv.z; acc[2][3] += av.z * bv.w;
      acc[3][0] += av.w * bv.x; acc[3][1] += av.w * bv.y; acc[3][2] += av.w * bv.z; acc[3][3] += av.w * bv.w;
    }
    __syncthreads();
  }

#pragma unroll
  for (int i = 0; i < 4; i++) {
    int m = mbase + (ty << 2) + i;
    if (m >= M) continue;
#pragma unroll
    for (int j = 0; j < 4; j++) {
      int n = nbase + (tx << 2) + j;
      if (n >= N) continue;
      float v = acc[i][j];
      if (bias) v += bias[n];
      if (Cin) v += Cin[(size_t)m * N + n];
      C[(size_t)m * N + n] = v;
    }
  }
}

__global__ __launch_bounds__(256) void gemm_nt(
    const float* __restrict__ A, const float* __restrict__ B,
    const float* __restrict__ bias, float* __restrict__ C,
    int M, int N, int K)
{
  __shared__ float As[16 * 64];
  __shared__ float Bs[16 * 64];
  gemm_nt_body(A, B, bias, nullptr, C, M, N, K, As, Bs);
}

// Step GEMM: two halves (fw/bw) selected by blockIdx.z.
// Co[m,n] = Ci[m,n] + state[m,:]·Whh[n,:]   (N=1200, K=300)
__global__ __launch_bounds__(256) void step_gemm(
    const float* A0, const float* A1, const float* B0, const float* B1,
    const float* Ci0, const float* Ci1, float* Co0, float* Co1, int Mh)
{
  __shared__ float As[16 * 64];
  __shared__ float Bs[16 * 64];
  const float* A = blockIdx.z ? A1 : A0;
  const float* Bm = blockIdx.z ? B1 : B0;
  const float* Ci = blockIdx.z ? Ci1 : Ci0;
  float* Co = blockIdx.z ? Co1 : Co0;
  gemm_nt_body(A, Bm, nullptr, Ci, Co, Mh, 1200, 300, As, Bs);
}

// LSTM elementwise gates. g rows are (n,1200): [i|f|g|o] blocks of 300.
__global__ __launch_bounds__(256) void lstm_elem(
    const float* __restrict__ g0, const float* __restrict__ g1,
    float* __restrict__ sh0, float* __restrict__ sc0,
    float* __restrict__ sh1, float* __restrict__ sc1,
    float* __restrict__ out0, float* __restrict__ out1, int Mh)
{
  const int half = blockIdx.y;
  const float* g = half ? g1 : g0;
  float* sh = half ? sh1 : sh0;
  float* sc = half ? sc1 : sc0;
  float* out = half ? out1 : out0;
  int idx = blockIdx.x * 256 + threadIdx.x;
  if (idx >= Mh * 300) return;
  int n = idx / 300, hh = idx - n * 300;
  const float* grow = g + (size_t)n * 1200;
  float gi = grow[hh];
  float gf = grow[300 + hh];
  float gg = grow[600 + hh];
  float go = grow[900 + hh];
  float si = 1.f / (1.f + expf(-gi));
  float sf = 1.f / (1.f + expf(-gf));
  float so = 1.f / (1.f + expf(-go));
  float c = sf * sc[idx] + si * tanhf(gg);
  float h = so * tanhf(c);
  sc[idx] = c;
  sh[idx] = h;
  if (out) out[idx] = h;
}

// Embedding gather into comb (T,256,300), float4 granularity (300 = 75*4).
__global__ void embed_kernel(
    const int* __restrict__ prem, const int* __restrict__ hyp,
    const float* __restrict__ embW, float* __restrict__ comb)
{
  size_t i = (size_t)blockIdx.x * 256 + threadIdx.x;
  if (i >= (size_t)64 * 256 * 75) return;
  int d4 = (int)(i % 75);
  size_t r = i / 75;
  int n = (int)(r % 256);
  int t = (int)(r / 256);
  int id = (n < 128) ? prem[t * 128 + n] : hyp[t * 128 + (n - 128)];
  float4 v = *(const float4*)(embW + (size_t)id * 300 + d4 * 4);
  *(float4*)(comb + ((size_t)t * 256 + n) * 300 + d4 * 4) = v;
}

// Precompute Wm-weighted norms (sqrt) per (dir,t,n,l) and plain L2 row norms.
__global__ __launch_bounds__(320) void norm_kernel(
    const float* __restrict__ hs_fw, const float* __restrict__ hs_bw,
    const float* __restrict__ mp_W,
    float* __restrict__ nm2, float* __restrict__ pnorm)
{
  const int t = blockIdx.x, n = blockIdx.y, dir = blockIdx.z;
  const float* HS = dir ? hs_bw : hs_fw;
  const float* row = HS + ((size_t)t * 256 + n) * 300;
  const float* Wm = mp_W + dir * 24000 + 6000;  // mp_W[1] or mp_W[5]
  __shared__ float sh[300];
  const int tid = threadIdx.x, g = tid >> 4, lane = tid & 15;
  for (int k = tid; k < 300; k += 320) sh[k] = row[k];
  __syncthreads();
  float s1 = 0.f, s2 = 0.f;
  for (int k = lane; k < 300; k += 16) {
    float x = sh[k];
    float w = Wm[g * 300 + k];
    s1 += x * x * w * w;
    if (g == 0) s2 += x * x;
  }
  for (int o = 8; o; o >>= 1) {
    s1 += __shfl_down(s1, o, 16);
    if (g == 0) s2 += __shfl_down(s2, o, 16);
  }
  if (lane == 0) {
    nm2[(((size_t)dir * 64 + t) * 256 + n) * 20 + g] = sqrtf(s1);
    if (g == 0) pnorm[((size_t)dir * 64 + t) * 256 + n] = sqrtf(s2);
  }
}

// Fused matching kernel: one block per (t, b, z). z = {fw_ph, bw_ph, fw_hp, bw_hp}.
// Writes 80 floats: [full(20) | maxp(20) | attm(20) | maxattm(20)] at m[t,b,z*80..].
__global__ __launch_bounds__(384) void match_kernel(
    const float* __restrict__ hs_fw, const float* __restrict__ hs_bw,
    const float* __restrict__ mp_W, const float* __restrict__ nm2,
    const float* __restrict__ pnorm, float* __restrict__ m_out)
{
  const int t = blockIdx.x, b = blockIdx.y, z = blockIdx.z;
  const int dir = z & 1;
  const float* HS = dir ? hs_bw : hs_fw;
  const int p_n = (z < 2) ? b : 128 + b;
  const int h_n = (z < 2) ? 128 + b : b;
  const int v_t = dir ? 0 : 63;
  const float* p_row = HS + ((size_t)t * 256 + p_n) * 300;
  const float* h_base = HS + (size_t)h_n * 300;  // + s*76800
  const float* v_row = HS + ((size_t)v_t * 256 + h_n) * 300;
  const float* Wset = mp_W + dir * 24000;
  const float* Wf = Wset;
  const float* Wm = Wset + 6000;
  const float* Wa = Wset + 12000;
  const float* Wma = Wset + 18000;
  const float* nmD = nm2 + (size_t)dir * 64 * 256 * 20;
  const float* pnD = pnorm + (size_t)dir * 64 * 256;

  __shared__ float sh_p[300], sh_v[300], sh_h[300], sh_hmean[300], sh_hmax[300];
  __shared__ float sh_w2m[6000];
  __shared__ float sh_att[64];
  __shared__ float sh_winv;
  __shared__ int sh_idx;

  const int tid = threadIdx.x;
  const int g = tid >> 4, lane = tid & 15;

  for (int k = tid; k < 300; k += 384) { sh_p[k] = p_row[k]; sh_v[k] = v_row[k]; }
  for (int k = tid; k < 6000; k += 384) { float w = Wm[k]; sh_w2m[k] = w * w; }
  __syncthreads();

  float* mrow = m_out + ((size_t)t * 128 + b) * 320 + z * 80;

  // ---- full match (vs v_row) ----
  if (g < 20) {
    float num = 0.f, pn2 = 0.f, vn2 = 0.f;
    const float* wr = Wf + g * 300;
    for (int k = lane; k < 300; k += 16) {
      float w = wr[k]; float w2 = w * w;
      float pv = sh_p[k], vv = sh_v[k];
      num += pv * vv * w2; pn2 += pv * pv * w2; vn2 += vv * vv * w2;
    }
    for (int o = 8; o; o >>= 1) {
      num += __shfl_down(num, o, 16);
      pn2 += __shfl_down(pn2, o, 16);
      vn2 += __shfl_down(vn2, o, 16);
    }
    if (lane == 0) mrow[g] = num / (sqrtf(pn2) * sqrtf(vn2) + EPSF);
  }

  // ---- maxp over s + attention row ----
  float pn_m = 0.f;
  if (g < 20 && lane == 0) pn_m = nmD[((size_t)t * 256 + p_n) * 20 + g];
  const float pnorm_t = pnD[t * 256 + p_n];
  float runmax = -1e30f;
  for (int s = 0; s < 64; s++) {
    __syncthreads();
    for (int k = tid; k < 300; k += 384) sh_h[k] = h_base[(size_t)s * 76800 + k];
    __syncthreads();
    if (g < 20) {
      float num = 0.f;
      const float* w2 = sh_w2m + g * 300;
      for (int k = lane; k < 300; k += 16) num += sh_p[k] * sh_h[k] * w2[k];
      for (int o = 8; o; o >>= 1) num += __shfl_down(num, o, 16);
      if (lane == 0) {
        float hn = nmD[((size_t)s * 256 + h_n) * 20 + g];
        float r = num / (pn_m * hn + EPSF);
        runmax = fmaxf(runmax, r);
      }
    } else if (g == 20) {
      float num = 0.f;
      for (int k = lane; k < 300; k += 16) num += sh_p[k] * sh_h[k];
      for (int o = 8; o; o >>= 1) num += __shfl_down(num, o, 16);
      if (lane == 0) {
        float hnorm = pnD[s * 256 + h_n];
        sh_att[s] = num / ((pnorm_t + EPSF) * (hnorm + EPSF));
      }
    }
  }
  __syncthreads();
  if (g < 20 && lane == 0) mrow[20 + g] = runmax;

  if (tid == 0) {
    float ssum = 0.f, mx = -1e30f; int mi = 0;
    for (int s = 0; s < 64; s++) {
      float a = sh_att[s];
      ssum += a;
      if (a > mx) { mx = a; mi = s; }
    }
    sh_winv = 1.f / (ssum + EPSF);
    sh_idx = mi;
  }
  __syncthreads();
  const float winv = sh_winv;
  const int mi = sh_idx;

  // hmean (attention-weighted) and hmax (argmax row)
  for (int k = tid; k < 300; k += 384) {
    float acc = 0.f;
    for (int s = 0; s < 64; s++) acc += sh_att[s] * h_base[(size_t)s * 76800 + k];
    sh_hmean[k] = acc * winv;
    sh_hmax[k] = h_base[(size_t)mi * 76800 + k];
  }
  __syncthreads();

  if (g < 20) {
    // attm (p vs hmean, Wa)
    {
      float num = 0.f, pn2 = 0.f, qn2 = 0.f;
      const float* wr = Wa + g * 300;
      for (int k = lane; k < 300; k += 16) {
        float w = wr[k]; float w2 = w * w;
        float pv = sh_p[k], qv = sh_hmean[k];
        num += pv * qv * w2; pn2 += pv * pv * w2; qn2 += qv * qv * w2;
      }
      for (int o = 8; o; o >>= 1) {
        num += __shfl_down(num, o, 16);
        pn2 += __shfl_down(pn2, o, 16);
        qn2 += __shfl_down(qn2, o, 16);
      }
      if (lane == 0) mrow[40 + g] = num / (sqrtf(pn2) * sqrtf(qn2) + EPSF);
    }
    // maxattm (p vs hmax, Wma)
    {
      float num = 0.f, pn2 = 0.f, qn2 = 0.f;
      const float* wr = Wma + g * 300;
      for (int k = lane; k < 300; k += 16) {
        float w = wr[k]; float w2 = w * w;
        float pv = sh_p[k], qv = sh_hmax[k];
        num += pv * qv * w2; pn2 += pv * pv * w2; qn2 += qv * qv * w2;
      }
      for (int o = 8; o; o >>= 1) {
        num += __shfl_down(num, o, 16);
        pn2 += __shfl_down(pn2, o, 16);
        qn2 += __shfl_down(qn2, o, 16);
      }
      if (lane == 0) mrow[60 + g] = num / (sqrtf(pn2) * sqrtf(qn2) + EPSF);
    }
  }
}

// Final MLP head: one block per batch row.
__global__ __launch_bounds__(256) void mlp_kernel(
    const float* __restrict__ shA0, const float* __restrict__ shA1,
    const float* __restrict__ bnG, const float* __restrict__ bnB,
    const float* __restrict__ W1, const float* __restrict__ b1,
    const float* __restrict__ W2, const float* __restrict__ b2,
    const float* __restrict__ outW, const float* __restrict__ outb,
    float* __restrict__ out)
{
  const int b = blockIdx.x;
  const int tid = threadIdx.x;
  __shared__ float x0[600], x1[600];
  const float inv = 1.0f / sqrtf(1.0f + 1e-5f);
  for (int j = tid; j < 600; j += 256) {
    float v = (j < 300) ? shA0[b * 300 + j] : shA1[b * 300 + (j - 300)];
    x0[j] = bnG[j] * v * inv + bnB[j];
  }
  __syncthreads();
  for (int j = tid; j < 600; j += 256) {
    float acc = b1[j];
    const float* w = W1 + (size_t)j * 600;
    for (int k = 0; k < 600; k++) acc += x0[k] * w[k];
    float r = fmaxf(acc, 0.f);
    x1[j] = bnG[600 + j] * r * inv + bnB[600 + j];
  }
  __syncthreads();
  for (int j = tid; j < 600; j += 256) {
    float acc = b2[j];
    const float* w = W2 + (size_t)j * 600;
    for (int k = 0; k < 600; k++) acc += x1[k] * w[k];
    float r = fmaxf(acc, 0.f);
    x0[j] = bnG[1200 + j] * r * inv + bnB[1200 + j];
  }
  __syncthreads();
  if (tid < 3) {
    float acc = outb[tid];
    const float* w = outW + tid * 600;
    for (int k = 0; k < 600; k++) acc += x0[k] * w[k];
    out[b * 3 + tid] = acc;
  }
}

// ---------------------------------------------------------------------------
extern "C" void kernel_launch(void* const* d_in, const int* in_sizes, int n_in,
                              void* d_out, int out_size, void* d_ws, size_t ws_size,
                              hipStream_t stream) {
  const int* premise = (const int*)d_in[0];
  const int* hypothesis = (const int*)d_in[1];
  const float* embW = (const float*)d_in[2];
  const float* cWih = (const float*)d_in[3];
  const float* cWhh = (const float*)d_in[4];
  const float* cb = (const float*)d_in[5];
  const float* mpW = (const float*)d_in[6];
  const float* aWihF = (const float*)d_in[7];
  const float* aWhhF = (const float*)d_in[8];
  const float* abF = (const float*)d_in[9];
  const float* aWihB = (const float*)d_in[10];
  const float* aWhhB = (const float*)d_in[11];
  const float* abB = (const float*)d_in[12];
  const float* bnG = (const float*)d_in[13];
  const float* bnB = (const float*)d_in[14];
  const float* W1 = (const float*)d_in[15];
  const float* b1 = (const float*)d_in[16];
  const float* W2 = (const float*)d_in[17];
  const float* b2 = (const float*)d_in[18];
  const float* outW = (const float*)d_in[19];
  const float* outb = (const float*)d_in[20];
  float* out = (float*)d_out;

  float* ws = (float*)d_ws;
  // workspace layout (floats)
  float* comb  = ws + 0;           // 4,915,200  (T,256,300)
  float* gates = ws + 4915200;     // 19,660,800 (T,256,1200); reused for agg gates
  float* hsfw  = ws + 24576000;    // 4,915,200
  float* hsbw  = ws + 29491200;    // 4,915,200
  float* nm2   = ws + 34406400;    // 655,360   [2][64][256][20]
  float* pnorm = ws + 35061760;    // 32,768    [2][64][256]
  float* mbuf  = ws + 35094528;    // 2,621,440 (T,128,320)
  float* shc   = ws + 37715968;    // 153,600   ctx h state [2][256][300]
  float* scc   = ws + 37869568;    // 153,600   ctx c state
  float* sha   = ws + 38023168;    // 76,800    agg h state [2][128][300]
  float* sca   = ws + 38099968;    // 76,800    agg c state
  float* gtmp  = ws + 38176768;    // 614,400   step gate scratch [2][256][1200]
  // total: 38,791,168 floats = ~148 MB

  // 1) embed -> comb
  embed_kernel<<<dim3(4800), dim3(256), 0, stream>>>(premise, hypothesis, embW, comb);

  // 2) ctx input gates: gates = comb @ cWih^T + cb  (M=16384, N=1200, K=300)
  gemm_nt<<<dim3(19, 256), dim3(256), 0, stream>>>(comb, cWih, cb, gates, 16384, 1200, 300);

  // 3) zero all LSTM states (one contiguous region)
  hipMemsetAsync(shc, 0, (size_t)(153600 + 153600 + 76800 + 76800) * sizeof(float), stream);

  // 4) context LSTM, fw+bw fused per step
  for (int t = 0; t < 64; t++) {
    step_gemm<<<dim3(19, 4, 2), dim3(256), 0, stream>>>(
        shc, shc + 76800, cWhh, cWhh,
        gates + (size_t)t * 307200, gates + (size_t)(63 - t) * 307200,
        gtmp, gtmp + 307200, 256);
    lstm_elem<<<dim3(300, 2), dim3(256), 0, stream>>>(
        gtmp, gtmp + 307200, shc, scc, shc + 76800, scc + 76800,
        hsfw + (size_t)t * 76800, hsbw + (size_t)(63 - t) * 76800, 256);
  }

  // 5) matching norms precompute
  norm_kernel<<<dim3(64, 256, 2), dim3(320), 0, stream>>>(hsfw, hsbw, mpW, nm2, pnorm);

  // 6) fused matching -> mbuf (T,128,320)
  match_kernel<<<dim3(64, 128, 4), dim3(384), 0, stream>>>(hsfw, hsbw, mpW, nm2, pnorm, mbuf);

  // 7) agg input gates (reuse gates region): f then b
  float* gaf = gates;
  float* gab = gates + 9830400;
  gemm_nt<<<dim3(19, 128), dim3(256), 0, stream>>>(mbuf, aWihF, abF, gaf, 8192, 1200, 320);
  gemm_nt<<<dim3(19, 128), dim3(256), 0, stream>>>(mbuf, aWihB, abB, gab, 8192, 1200, 320);

  // 8) aggregation LSTM, f+b fused per step (only final states needed)
  for (int t = 0; t < 64; t++) {
    step_gemm<<<dim3(19, 2, 2), dim3(256), 0, stream>>>(
        sha, sha + 38400, aWhhF, aWhhB,
        gaf + (size_t)t * 153600, gab + (size_t)(63 - t) * 153600,
        gtmp, gtmp + 153600, 128);
    lstm_elem<<<dim3(150, 2), dim3(256), 0, stream>>>(
        gtmp, gtmp + 153600, sha, sca, sha + 38400, sca + 38400,
        nullptr, nullptr, 128);
  }

  // 9) MLP head
  mlp_kernel<<<dim3(128), dim3(256), 0, stream>>>(
      sha, sha + 38400, bnG, bnB, W1, b1, W2, b2, outW, outb, out);
}

// Round 2
// 5718.992 us; speedup vs baseline: 2.2989x; 2.2989x over previous
//
#include <hip/hip_runtime.h>
#include <cstddef>
#include <cstdint>
#include <math.h>

#define EPSF 1e-8f

// Model dims (fixed)
// T=64, B=128, D=300, H=300, L=20, AH=300, N2=2B=256

// ---------------------------------------------------------------------------
// Generic NT GEMM body: C[m,n] = (bias?bias[n]:0) + (Cin?Cin[m,n]:0) + sum_k A[m,k]*B[n,k]
// ---------------------------------------------------------------------------
__device__ __forceinline__ void gemm_nt_body(
    const float* __restrict__ A, const float* __restrict__ B,
    const float* __restrict__ bias, const float* __restrict__ Cin,
    float* __restrict__ C, int M, int N, int K,
    float* As, float* Bs)
{
  const int tid = threadIdx.x;
  const int tx = tid & 15, ty = tid >> 4;
  const int mbase = blockIdx.y << 6, nbase = blockIdx.x << 6;
  const int lm = tid >> 2;
  const int lk = (tid & 3) << 2;
  float acc[4][4];
#pragma unroll
  for (int i = 0; i < 4; i++)
#pragma unroll
    for (int j = 0; j < 4; j++) acc[i][j] = 0.f;

  for (int kk = 0; kk < K; kk += 16) {
    {
      int m = mbase + lm;
      int kbase = kk + lk;
      float4 v = make_float4(0.f, 0.f, 0.f, 0.f);
      if (m < M) {
        if (kbase + 4 <= K) {
          v = *(const float4*)(A + (size_t)m * K + kbase);
        } else {
          const float* src = A + (size_t)m * K;
          float t0 = (kbase + 0 < K) ? src[kbase + 0] : 0.f;
          float t1 = (kbase + 1 < K) ? src[kbase + 1] : 0.f;
          float t2 = (kbase + 2 < K) ? src[kbase + 2] : 0.f;
          float t3 = (kbase + 3 < K) ? src[kbase + 3] : 0.f;
          v = make_float4(t0, t1, t2, t3);
        }
      }
      As[(lk + 0) * 64 + lm] = v.x;
      As[(lk + 1) * 64 + lm] = v.y;
      As[(lk + 2) * 64 + lm] = v.z;
      As[(lk + 3) * 64 + lm] = v.w;
    }
    {
      int n = nbase + lm;
      int kbase = kk + lk;
      float4 v = make_float4(0.f, 0.f, 0.f, 0.f);
      if (n < N) {
        if (kbase + 4 <= K) {
          v = *(const float4*)(B + (size_t)n * K + kbase);
        } else {
          const float* src = B + (size_t)n * K;
          float t0 = (kbase + 0 < K) ? src[kbase + 0] : 0.f;
          float t1 = (kbase + 1 < K) ? src[kbase + 1] : 0.f;
          float t2 = (kbase + 2 < K) ? src[kbase + 2] : 0.f;
          float t3 = (kbase + 3 < K) ? src[kbase + 3] : 0.f;
          v = make_float4(t0, t1, t2, t3);
        }
      }
      Bs[(lk + 0) * 64 + lm] = v.x;
      Bs[(lk + 1) * 64 + lm] = v.y;
      Bs[(lk + 2) * 64 + lm] = v.z;
      Bs[(lk + 3) * 64 + lm] = v.w;
    }
    __syncthreads();
#pragma unroll
    for (int k = 0; k < 16; k++) {
      float4 av = *(const float4*)(As + k * 64 + (ty << 2));
      float4 bv = *(const float4*)(Bs + k * 64 + (tx << 2));
      acc[0][0] += av.x * bv.x; acc[0][1] += av.x * bv.y; acc[0][2] += av.x * bv.z; acc[0][3] += av.x * bv.w;
      acc[1][0] += av.y * bv.x; acc[1][1] += av.y * bv.y; acc[1][2] += av.y * bv.z; acc[1][3] += av.y * bv.w;
      acc[2][0] += av.z * bv.x; acc[2][1] += av.z * bv.y; acc[2][2] += av.z * bv.z; acc[2][3] += av.z * bv.w;
      acc[3][0] += av.w * bv.x; acc[3][1] += av.w * bv.y; acc[3][2] += av.w * bv.z; acc[3][3] += av.w * bv.w;
    }
    __syncthreads();
  }

#pragma unroll
  for (int i = 0; i < 4; i++) {
    int m = mbase + (ty << 2) + i;
    if (m >= M) continue;
#pragma unroll
    for (int j = 0; j < 4; j++) {
      int n = nbase + (tx << 2) + j;
      if (n >= N) continue;
      float v = acc[i][j];
      if (bias) v += bias[n];
      if (Cin) v += Cin[(size_t)m * N + n];
      C[(size_t)m * N + n] = v;
    }
  }
}

__global__ __launch_bounds__(256) void gemm_nt(
    const float* __restrict__ A, const float* __restrict__ B,
    const float* __restrict__ bias, float* __restrict__ C,
    int M, int N, int K)
{
  __shared__ float As[16 * 64];
  __shared__ float Bs[16 * 64];
  gemm_nt_body(A, B, bias, nullptr, C, M, N, K, As, Bs);
}

__global__ __launch_bounds__(256) void step_gemm(
    const float* A0, const float* A1, const float* B0, const float* B1,
    const float* Ci0, const float* Ci1, float* Co0, float* Co1, int Mh)
{
  __shared__ float As[16 * 64];
  __shared__ float Bs[16 * 64];
  const float* A = blockIdx.z ? A1 : A0;
  const float* Bm = blockIdx.z ? B1 : B0;
  const float* Ci = blockIdx.z ? Ci1 : Ci0;
  float* Co = blockIdx.z ? Co1 : Co0;
  gemm_nt_body(A, Bm, nullptr, Ci, Co, Mh, 1200, 300, As, Bs);
}

__global__ __launch_bounds__(256) void lstm_elem(
    const float* __restrict__ g0, const float* __restrict__ g1,
    float* __restrict__ sh0, float* __restrict__ sc0,
    float* __restrict__ sh1, float* __restrict__ sc1,
    float* __restrict__ out0, float* __restrict__ out1, int Mh)
{
  const int half = blockIdx.y;
  const float* g = half ? g1 : g0;
  float* sh = half ? sh1 : sh0;
  float* sc = half ? sc1 : sc0;
  float* out = half ? out1 : out0;
  int idx = blockIdx.x * 256 + threadIdx.x;
  if (idx >= Mh * 300) return;
  int n = idx / 300, hh = idx - n * 300;
  const float* grow = g + (size_t)n * 1200;
  float gi = grow[hh];
  float gf = grow[300 + hh];
  float gg = grow[600 + hh];
  float go = grow[900 + hh];
  float si = 1.f / (1.f + expf(-gi));
  float sf = 1.f / (1.f + expf(-gf));
  float so = 1.f / (1.f + expf(-go));
  float c = sf * sc[idx] + si * tanhf(gg);
  float h = so * tanhf(c);
  sc[idx] = c;
  sh[idx] = h;
  if (out) out[idx] = h;
}

__global__ void embed_kernel(
    const int* __restrict__ prem, const int* __restrict__ hyp,
    const float* __restrict__ embW, float* __restrict__ comb)
{
  size_t i = (size_t)blockIdx.x * 256 + threadIdx.x;
  if (i >= (size_t)64 * 256 * 75) return;
  int d4 = (int)(i % 75);
  size_t r = i / 75;
  int n = (int)(r % 256);
  int t = (int)(r / 256);
  int id = (n < 128) ? prem[t * 128 + n] : hyp[t * 128 + (n - 128)];
  float4 v = *(const float4*)(embW + (size_t)id * 300 + d4 * 4);
  *(float4*)(comb + ((size_t)t * 256 + n) * 300 + d4 * 4) = v;
}

// ---------------------------------------------------------------------------
// norm4: weighted norms for ALL FOUR W sets per (dir,t,n,l): nm4[dir][w][t][n][20]
// plus plain row norms pnorm[dir][t][n].
// ---------------------------------------------------------------------------
__global__ __launch_bounds__(320) void norm4_kernel(
    const float* __restrict__ hs_fw, const float* __restrict__ hs_bw,
    const float* __restrict__ mp_W,
    float* __restrict__ nm4, float* __restrict__ pnorm)
{
  const int t = blockIdx.x, n = blockIdx.y, dir = blockIdx.z;
  const float* HS = dir ? hs_bw : hs_fw;
  const float* row = HS + ((size_t)t * 256 + n) * 300;
  __shared__ float sh[300];
  const int tid = threadIdx.x, g = tid >> 4, lane = tid & 15;
  for (int k = tid; k < 300; k += 320) sh[k] = row[k];
  __syncthreads();
  if (g == 0) {
    float s2 = 0.f;
    for (int k = lane; k < 300; k += 16) { float x = sh[k]; s2 += x * x; }
    for (int o = 8; o; o >>= 1) s2 += __shfl_down(s2, o, 16);
    if (lane == 0) pnorm[((size_t)dir * 64 + t) * 256 + n] = sqrtf(s2);
  }
#pragma unroll
  for (int wset = 0; wset < 4; wset++) {
    const float* W = mp_W + dir * 24000 + wset * 6000 + g * 300;
    float s1 = 0.f;
    for (int k = lane; k < 300; k += 16) {
      float x = sh[k];
      float w = W[k];
      s1 += x * x * w * w;
    }
    for (int o = 8; o; o >>= 1) s1 += __shfl_down(s1, o, 16);
    if (lane == 0)
      nm4[((((size_t)dir * 4 + wset) * 64 + t) * 256 + n) * 20 + g] = sqrtf(s1);
  }
}

// ---------------------------------------------------------------------------
// att: per (b,z), att[64,64] cosine GEMM -> normalized w (watt) + argmax idx.
// ---------------------------------------------------------------------------
__global__ __launch_bounds__(256) void att_kernel(
    const float* __restrict__ hs_fw, const float* __restrict__ hs_bw,
    const float* __restrict__ pnorm,
    float* __restrict__ watt, int* __restrict__ idxbuf)
{
  const int b = blockIdx.x, z = blockIdx.y;
  const int dir = z & 1;
  const float* HS = dir ? hs_bw : hs_fw;
  const int p_n = (z < 2) ? b : 128 + b;
  const int h_n = (z < 2) ? 128 + b : b;
  const float* pnD = pnorm + (size_t)dir * 16384;

  __shared__ float pch[64 * 100];
  __shared__ float hch[64 * 100];
  __shared__ float att[64 * 65];
  __shared__ float winv_sh[64];

  const int tid = threadIdx.x;
  const int i = tid >> 4, j = tid & 15;
  float acc[4][4];
#pragma unroll
  for (int a = 0; a < 4; a++)
#pragma unroll
    for (int c = 0; c < 4; c++) acc[a][c] = 0.f;

  for (int kc = 0; kc < 300; kc += 100) {
    for (int e = tid; e < 1600; e += 256) {
      int row = e / 25, kq = e - row * 25;
      float4 v = *(const float4*)(HS + ((size_t)row * 256 + p_n) * 300 + kc + kq * 4);
      *(float4*)&pch[row * 100 + kq * 4] = v;
      float4 w = *(const float4*)(HS + ((size_t)row * 256 + h_n) * 300 + kc + kq * 4);
      *(float4*)&hch[row * 100 + kq * 4] = w;
    }
    __syncthreads();
#pragma unroll 5
    for (int kq = 0; kq < 25; kq++) {
      float4 av[4], bv[4];
#pragma unroll
      for (int a = 0; a < 4; a++) av[a] = *(const float4*)&pch[(i + 16 * a) * 100 + kq * 4];
#pragma unroll
      for (int c = 0; c < 4; c++) bv[c] = *(const float4*)&hch[(j + 16 * c) * 100 + kq * 4];
#pragma unroll
      for (int a = 0; a < 4; a++)
#pragma unroll
        for (int c = 0; c < 4; c++)
          acc[a][c] += av[a].x * bv[c].x + av[a].y * bv[c].y + av[a].z * bv[c].z + av[a].w * bv[c].w;
    }
    __syncthreads();
  }

#pragma unroll
  for (int a = 0; a < 4; a++) {
    int t = i + 16 * a;
    float pn = pnD[t * 256 + p_n] + EPSF;
#pragma unroll
    for (int c = 0; c < 4; c++) {
      int s = j + 16 * c;
      float hn = pnD[s * 256 + h_n] + EPSF;
      att[t * 65 + s] = acc[a][c] / (pn * hn);
    }
  }
  __syncthreads();
  if (tid < 64) {
    int t = tid;
    float ssum = 0.f, mx = -1e30f; int mi = 0;
    for (int s = 0; s < 64; s++) {
      float a = att[t * 65 + s];
      ssum += a;
      if (a > mx) { mx = a; mi = s; }
    }
    winv_sh[t] = 1.f / (ssum + EPSF);
    idxbuf[((size_t)z * 128 + b) * 64 + t] = mi;
  }
  __syncthreads();
  for (int e = tid; e < 4096; e += 256) {
    int t = e >> 6, s = e & 63;
    watt[((size_t)z * 128 + b) * 4096 + t * 64 + s] = att[t * 65 + s] * winv_sh[t];
  }
}

// ---------------------------------------------------------------------------
// hmean: per (b,z): hmean[t,k] = sum_s w[t,s]*h[s,k]
// ---------------------------------------------------------------------------
__global__ __launch_bounds__(256) void hmean_kernel(
    const float* __restrict__ hs_fw, const float* __restrict__ hs_bw,
    const float* __restrict__ watt, float* __restrict__ hmeanbuf)
{
  const int b = blockIdx.x, z = blockIdx.y;
  const int dir = z & 1;
  const float* HS = dir ? hs_bw : hs_fw;
  const int h_n = (z < 2) ? 128 + b : b;

  __shared__ float wsh[64 * 65];
  __shared__ float hch[64 * 128];

  const int tid = threadIdx.x;
  const int ti = tid >> 4, kj = tid & 15;
  const float* wsrc = watt + ((size_t)z * 128 + b) * 4096;
  for (int e = tid; e < 4096; e += 256) {
    int t = e >> 6, s = e & 63;
    wsh[t * 65 + s] = wsrc[t * 64 + s];
  }

  for (int kbase = 0; kbase < 300; kbase += 128) {
    int kw = min(128, 300 - kbase);
    int nf4 = kw >> 2;  // 32,32,11
    __syncthreads();
    for (int e = tid; e < 64 * nf4; e += 256) {
      int row = e / nf4, q = e - row * nf4;
      float4 v = *(const float4*)(HS + ((size_t)row * 256 + h_n) * 300 + kbase + q * 4);
      *(float4*)&hch[row * 128 + q * 4] = v;
    }
    __syncthreads();
    float acc[4][8];
#pragma unroll
    for (int a = 0; a < 4; a++)
#pragma unroll
      for (int c = 0; c < 8; c++) acc[a][c] = 0.f;
    for (int s = 0; s < 64; s++) {
      float4 h0 = *(const float4*)&hch[s * 128 + 4 * kj];
      float4 h1 = *(const float4*)&hch[s * 128 + 4 * (kj + 16)];
#pragma unroll
      for (int a = 0; a < 4; a++) {
        float w = wsh[(4 * ti + a) * 65 + s];
        acc[a][0] += w * h0.x; acc[a][1] += w * h0.y; acc[a][2] += w * h0.z; acc[a][3] += w * h0.w;
        acc[a][4] += w * h1.x; acc[a][5] += w * h1.y; acc[a][6] += w * h1.z; acc[a][7] += w * h1.w;
      }
    }
#pragma unroll
    for (int a = 0; a < 4; a++) {
      int t = 4 * ti + a;
#pragma unroll
      for (int c = 0; c < 2; c++) {
        int kq = kj + 16 * c;
        if (kq * 4 < kw) {
          int k = kbase + kq * 4;
          float4 v = make_float4(acc[a][4 * c], acc[a][4 * c + 1], acc[a][4 * c + 2], acc[a][4 * c + 3]);
          *(float4*)&hmeanbuf[(((size_t)z * 128 + b) * 64 + t) * 300 + k] = v;
        }
      }
    }
  }
}

// ---------------------------------------------------------------------------
// maxp: per (b,z,tt): num[t,s,l] GEMM with register tiles, fused max over s.
// 128 threads: t_loc=tid>>4 (8), sg=(tid>>1)&7, lg=tid&1 (l = lg*10+j).
// ---------------------------------------------------------------------------
__global__ __launch_bounds__(128) void maxp_kernel(
    const float* __restrict__ hs_fw, const float* __restrict__ hs_bw,
    const float* __restrict__ mp_W, const float* __restrict__ nm4,
    float* __restrict__ m_out)
{
  const int b = blockIdx.x, z = blockIdx.y, tt = blockIdx.z;
  const int dir = z & 1;
  const float* HS = dir ? hs_bw : hs_fw;
  const int p_n = (z < 2) ? b : 128 + b;
  const int h_n = (z < 2) ? 128 + b : b;
  const int t_base = tt * 8;
  const float* Wm = mp_W + dir * 24000 + 6000;

  __shared__ float psh[8 * 100];
  __shared__ float hsh[64 * 100];
  __shared__ float wsh[20 * 100];

  const int tid = threadIdx.x;
  const int t_loc = tid >> 4;
  const int sg = (tid >> 1) & 7;
  const int lg = tid & 1;
  const int t = t_base + t_loc;

  float acc[8][10];
#pragma unroll
  for (int i = 0; i < 8; i++)
#pragma unroll
    for (int j = 0; j < 10; j++) acc[i][j] = 0.f;

  for (int kc = 0; kc < 300; kc += 100) {
    for (int e = tid; e < 200; e += 128) {
      int row = e / 25, q = e - row * 25;
      float4 v = *(const float4*)(HS + ((size_t)(t_base + row) * 256 + p_n) * 300 + kc + q * 4);
      *(float4*)&psh[row * 100 + q * 4] = v;
    }
    for (int e = tid; e < 1600; e += 128) {
      int row = e / 25, q = e - row * 25;
      float4 v = *(const float4*)(HS + ((size_t)row * 256 + h_n) * 300 + kc + q * 4);
      *(float4*)&hsh[row * 100 + q * 4] = v;
    }
    for (int e = tid; e < 500; e += 128) {
      int row = e / 25, q = e - row * 25;
      float4 w = *(const float4*)(Wm + (size_t)row * 300 + kc + q * 4);
      w.x *= w.x; w.y *= w.y; w.z *= w.z; w.w *= w.w;
      *(float4*)&wsh[row * 100 + q * 4] = w;
    }
    __syncthreads();
    for (int kq = 0; kq < 25; kq++) {
      float4 pv = *(const float4*)&psh[t_loc * 100 + kq * 4];
      float4 hv[8];
#pragma unroll
      for (int i = 0; i < 8; i++) hv[i] = *(const float4*)&hsh[(sg + 8 * i) * 100 + kq * 4];
#pragma unroll
      for (int j = 0; j < 10; j++) {
        float4 wv = *(const float4*)&wsh[(lg * 10 + j) * 100 + kq * 4];
        float pwx = pv.x * wv.x, pwy = pv.y * wv.y, pwz = pv.z * wv.z, pww = pv.w * wv.w;
#pragma unroll
        for (int i = 0; i < 8; i++)
          acc[i][j] += hv[i].x * pwx + hv[i].y * pwy + hv[i].z * pwz + hv[i].w * pww;
      }
    }
    __syncthreads();
  }

  const float* nmD = nm4 + ((size_t)dir * 4 + 1) * 327680;
  float pn[10], rmax[10];
#pragma unroll
  for (int j = 0; j < 10; j++) {
    pn[j] = nmD[((size_t)t * 256 + p_n) * 20 + lg * 10 + j];
    rmax[j] = -1e30f;
  }
#pragma unroll
  for (int i = 0; i < 8; i++) {
    int s = sg + 8 * i;
#pragma unroll
    for (int j = 0; j < 10; j++) {
      float hn = nmD[((size_t)s * 256 + h_n) * 20 + lg * 10 + j];
      float r = acc[i][j] / (pn[j] * hn + EPSF);
      rmax[j] = fmaxf(rmax[j], r);
    }
  }
#pragma unroll
  for (int off = 8; off >= 2; off >>= 1)
#pragma unroll
    for (int j = 0; j < 10; j++)
      rmax[j] = fmaxf(rmax[j], __shfl_down(rmax[j], off));
  if (sg == 0) {
    float* mrow = m_out + ((size_t)t * 128 + b) * 320 + z * 80;
#pragma unroll
    for (int j = 0; j < 10; j++) mrow[20 + lg * 10 + j] = rmax[j];
  }
}

// ---------------------------------------------------------------------------
// rest: per (b,z): full / attm / maxattm for all t. W^2 staged once in LDS.
// ---------------------------------------------------------------------------
__global__ __launch_bounds__(320) void rest_kernel(
    const float* __restrict__ hs_fw, const float* __restrict__ hs_bw,
    const float* __restrict__ mp_W, const float* __restrict__ nm4,
    const float* __restrict__ hmeanbuf, const int* __restrict__ idxbuf,
    float* __restrict__ m_out)
{
  const int b = blockIdx.x, z = blockIdx.y;
  const int dir = z & 1;
  const float* HS = dir ? hs_bw : hs_fw;
  const int p_n = (z < 2) ? b : 128 + b;
  const int h_n = (z < 2) ? 128 + b : b;
  const int v_t = dir ? 0 : 63;

  __shared__ float w2f[6000], w2a[6000], w2m[6000];
  __shared__ float vsh[300], psh[300], hmsh[300], hxsh[300];

  const int tid = threadIdx.x;
  const int g = tid >> 4, lane = tid & 15;
  const float* Wf = mp_W + dir * 24000;
  const float* Wa = Wf + 12000;
  const float* Wma = Wf + 18000;
  for (int e = tid; e < 6000; e += 320) {
    float a = Wf[e], bb = Wa[e], c = Wma[e];
    w2f[e] = a * a; w2a[e] = bb * bb; w2m[e] = c * c;
  }
  for (int e = tid; e < 300; e += 320)
    vsh[e] = HS[((size_t)v_t * 256 + h_n) * 300 + e];
  __syncthreads();

  const float* base0 = nm4 + ((size_t)dir * 4 + 0) * 327680;
  const float* base2 = nm4 + ((size_t)dir * 4 + 2) * 327680;
  const float* base3 = nm4 + ((size_t)dir * 4 + 3) * 327680;
  const float vnf = base0[((size_t)v_t * 256 + h_n) * 20 + g];

  for (int t = 0; t < 64; t++) {
    int idx = idxbuf[((size_t)z * 128 + b) * 64 + t];
    __syncthreads();
    for (int e = tid; e < 300; e += 320) {
      psh[e] = HS[((size_t)t * 256 + p_n) * 300 + e];
      hmsh[e] = hmeanbuf[(((size_t)z * 128 + b) * 64 + t) * 300 + e];
      hxsh[e] = HS[((size_t)idx * 256 + h_n) * 300 + e];
    }
    __syncthreads();
    float nf = 0.f, na = 0.f, qa = 0.f, nm = 0.f;
#pragma unroll
    for (int c = 0; c < 5; c++) {
      int k4 = lane + 16 * c;
      if (k4 < 75) {
        float4 p = *(const float4*)&psh[4 * k4];
        float4 v = *(const float4*)&vsh[4 * k4];
        float4 hm = *(const float4*)&hmsh[4 * k4];
        float4 hx = *(const float4*)&hxsh[4 * k4];
        float4 wf = *(const float4*)&w2f[g * 300 + 4 * k4];
        float4 wa = *(const float4*)&w2a[g * 300 + 4 * k4];
        float4 wm = *(const float4*)&w2m[g * 300 + 4 * k4];
        nf += p.x * v.x * wf.x + p.y * v.y * wf.y + p.z * v.z * wf.z + p.w * v.w * wf.w;
        na += p.x * hm.x * wa.x + p.y * hm.y * wa.y + p.z * hm.z * wa.z + p.w * hm.w * wa.w;
        qa += hm.x * hm.x * wa.x + hm.y * hm.y * wa.y + hm.z * hm.z * wa.z + hm.w * hm.w * wa.w;
        nm += p.x * hx.x * wm.x + p.y * hx.y * wm.y + p.z * hx.z * wm.z + p.w * hx.w * wm.w;
      }
    }
#pragma unroll
    for (int o = 8; o; o >>= 1) {
      nf += __shfl_down(nf, o);
      na += __shfl_down(na, o);
      qa += __shfl_down(qa, o);
      nm += __shfl_down(nm, o);
    }
    if (lane == 0) {
      float pnf = base0[((size_t)t * 256 + p_n) * 20 + g];
      float pna = base2[((size_t)t * 256 + p_n) * 20 + g];
      float pnm = base3[((size_t)t * 256 + p_n) * 20 + g];
      float qnm = base3[((size_t)idx * 256 + h_n) * 20 + g];
      float* mrow = m_out + ((size_t)t * 128 + b) * 320 + z * 80;
      mrow[g] = nf / (pnf * vnf + EPSF);
      mrow[40 + g] = na / (pna * sqrtf(qa) + EPSF);
      mrow[60 + g] = nm / (pnm * qnm + EPSF);
    }
  }
}

// ---------------------------------------------------------------------------
__global__ __launch_bounds__(256) void mlp_kernel(
    const float* __restrict__ shA0, const float* __restrict__ shA1,
    const float* __restrict__ bnG, const float* __restrict__ bnB,
    const float* __restrict__ W1, const float* __restrict__ b1,
    const float* __restrict__ W2, const float* __restrict__ b2,
    const float* __restrict__ outW, const float* __restrict__ outb,
    float* __restrict__ out)
{
  const int b = blockIdx.x;
  const int tid = threadIdx.x;
  __shared__ float x0[600], x1[600];
  const float inv = 1.0f / sqrtf(1.0f + 1e-5f);
  for (int j = tid; j < 600; j += 256) {
    float v = (j < 300) ? shA0[b * 300 + j] : shA1[b * 300 + (j - 300)];
    x0[j] = bnG[j] * v * inv + bnB[j];
  }
  __syncthreads();
  for (int j = tid; j < 600; j += 256) {
    float acc = b1[j];
    const float* w = W1 + (size_t)j * 600;
    for (int k = 0; k < 600; k++) acc += x0[k] * w[k];
    float r = fmaxf(acc, 0.f);
    x1[j] = bnG[600 + j] * r * inv + bnB[600 + j];
  }
  __syncthreads();
  for (int j = tid; j < 600; j += 256) {
    float acc = b2[j];
    const float* w = W2 + (size_t)j * 600;
    for (int k = 0; k < 600; k++) acc += x1[k] * w[k];
    float r = fmaxf(acc, 0.f);
    x0[j] = bnG[1200 + j] * r * inv + bnB[1200 + j];
  }
  __syncthreads();
  if (tid < 3) {
    float acc = outb[tid];
    const float* w = outW + tid * 600;
    for (int k = 0; k < 600; k++) acc += x0[k] * w[k];
    out[b * 3 + tid] = acc;
  }
}

// ---------------------------------------------------------------------------
extern "C" void kernel_launch(void* const* d_in, const int* in_sizes, int n_in,
                              void* d_out, int out_size, void* d_ws, size_t ws_size,
                              hipStream_t stream) {
  const int* premise = (const int*)d_in[0];
  const int* hypothesis = (const int*)d_in[1];
  const float* embW = (const float*)d_in[2];
  const float* cWih = (const float*)d_in[3];
  const float* cWhh = (const float*)d_in[4];
  const float* cb = (const float*)d_in[5];
  const float* mpW = (const float*)d_in[6];
  const float* aWihF = (const float*)d_in[7];
  const float* aWhhF = (const float*)d_in[8];
  const float* abF = (const float*)d_in[9];
  const float* aWihB = (const float*)d_in[10];
  const float* aWhhB = (const float*)d_in[11];
  const float* abB = (const float*)d_in[12];
  const float* bnG = (const float*)d_in[13];
  const float* bnB = (const float*)d_in[14];
  const float* W1 = (const float*)d_in[15];
  const float* b1 = (const float*)d_in[16];
  const float* W2 = (const float*)d_in[17];
  const float* b2 = (const float*)d_in[18];
  const float* outW = (const float*)d_in[19];
  const float* outb = (const float*)d_in[20];
  float* out = (float*)d_out;

  float* ws = (float*)d_ws;
  // workspace layout (floats)
  float* comb  = ws + 0;           // 4,915,200  (T,256,300)
  float* gates = ws + 4915200;     // 19,660,800 (T,256,1200); overlaid after ctx LSTM
  float* hsfw  = ws + 24576000;    // 4,915,200
  float* hsbw  = ws + 29491200;    // 4,915,200
  float* pnorm = ws + 34406400;    // 32,768    [2][64][256]
  float* mbuf  = ws + 35094528;    // 2,621,440 (T,128,320)
  float* shc   = ws + 37715968;    // 153,600   ctx h state [2][256][300]
  float* scc   = ws + 37869568;    // 153,600
  float* sha   = ws + 38023168;    // 76,800    agg h state [2][128][300]
  float* sca   = ws + 38099968;    // 76,800
  float* gtmp  = ws + 38176768;    // 614,400

  // overlays inside the dead ctx-gates region (valid between ctx LSTM and agg GEMMs)
  float* watt     = gates;                 // 2,097,152 [4][128][64][64]
  float* hmeanbuf = gates + 2097152;       // 9,830,400 [4][128][64][300]
  int*   idxbuf   = (int*)(gates + 11927552); // 32,768 [4][128][64]
  float* nm4      = gates + 11960320;      // 2,621,440 [2][4][64][256][20]

  // 1) embed
  embed_kernel<<<dim3(4800), dim3(256), 0, stream>>>(premise, hypothesis, embW, comb);

  // 2) ctx input gates
  gemm_nt<<<dim3(19, 256), dim3(256), 0, stream>>>(comb, cWih, cb, gates, 16384, 1200, 300);

  // 3) zero LSTM states
  hipMemsetAsync(shc, 0, (size_t)(153600 + 153600 + 76800 + 76800) * sizeof(float), stream);

  // 4) context LSTM
  for (int t = 0; t < 64; t++) {
    step_gemm<<<dim3(19, 4, 2), dim3(256), 0, stream>>>(
        shc, shc + 76800, cWhh, cWhh,
        gates + (size_t)t * 307200, gates + (size_t)(63 - t) * 307200,
        gtmp, gtmp + 307200, 256);
    lstm_elem<<<dim3(300, 2), dim3(256), 0, stream>>>(
        gtmp, gtmp + 307200, shc, scc, shc + 76800, scc + 76800,
        hsfw + (size_t)t * 76800, hsbw + (size_t)(63 - t) * 76800, 256);
  }

  // 5) norms (all 4 W sets) + plain norms
  norm4_kernel<<<dim3(64, 256, 2), dim3(320), 0, stream>>>(hsfw, hsbw, mpW, nm4, pnorm);

  // 6) matching pipeline
  att_kernel<<<dim3(128, 4), dim3(256), 0, stream>>>(hsfw, hsbw, pnorm, watt, idxbuf);
  hmean_kernel<<<dim3(128, 4), dim3(256), 0, stream>>>(hsfw, hsbw, watt, hmeanbuf);
  maxp_kernel<<<dim3(128, 4, 8), dim3(128), 0, stream>>>(hsfw, hsbw, mpW, nm4, mbuf);
  rest_kernel<<<dim3(128, 4), dim3(320), 0, stream>>>(hsfw, hsbw, mpW, nm4, hmeanbuf, idxbuf, mbuf);

  // 7) agg input gates (overwrite gates region; overlays fully consumed)
  float* gaf = gates;
  float* gab = gates + 9830400;
  gemm_nt<<<dim3(19, 128), dim3(256), 0, stream>>>(mbuf, aWihF, abF, gaf, 8192, 1200, 320);
  gemm_nt<<<dim3(19, 128), dim3(256), 0, stream>>>(mbuf, aWihB, abB, gab, 8192, 1200, 320);

  // 8) aggregation LSTM
  for (int t = 0; t < 64; t++) {
    step_gemm<<<dim3(19, 2, 2), dim3(256), 0, stream>>>(
        sha, sha + 38400, aWhhF, aWhhB,
        gaf + (size_t)t * 153600, gab + (size_t)(63 - t) * 153600,
        gtmp, gtmp + 153600, 128);
    lstm_elem<<<dim3(150, 2), dim3(256), 0, stream>>>(
        gtmp, gtmp + 153600, sha, sca, sha + 38400, sca + 38400,
        nullptr, nullptr, 128);
  }

  // 9) MLP head
  mlp_kernel<<<dim3(128), dim3(256), 0, stream>>>(
      sha, sha + 38400, bnG, bnB, W1, b1, W2, b2, outW, outb, out);
}

// Round 3
// 5499.390 us; speedup vs baseline: 2.3907x; 1.0399x over previous
//
#include <hip/hip_runtime.h>
#include <cstddef>
#include <cstdint>
#include <math.h>

#define EPSF 1e-8f

// Model dims (fixed): T=64, B=128, D=300, H=300, L=20, AH=300, N2=2B=256

// ---------------------------------------------------------------------------
// Generic NT GEMM: C[m,n] = bias[n] + sum_k A[m,k]*B[n,k]
// ---------------------------------------------------------------------------
__device__ __forceinline__ void gemm_nt_body(
    const float* __restrict__ A, const float* __restrict__ B,
    const float* __restrict__ bias, const float* __restrict__ Cin,
    float* __restrict__ C, int M, int N, int K,
    float* As, float* Bs)
{
  const int tid = threadIdx.x;
  const int tx = tid & 15, ty = tid >> 4;
  const int mbase = blockIdx.y << 6, nbase = blockIdx.x << 6;
  const int lm = tid >> 2;
  const int lk = (tid & 3) << 2;
  float acc[4][4];
#pragma unroll
  for (int i = 0; i < 4; i++)
#pragma unroll
    for (int j = 0; j < 4; j++) acc[i][j] = 0.f;

  for (int kk = 0; kk < K; kk += 16) {
    {
      int m = mbase + lm;
      int kbase = kk + lk;
      float4 v = make_float4(0.f, 0.f, 0.f, 0.f);
      if (m < M) {
        if (kbase + 4 <= K) {
          v = *(const float4*)(A + (size_t)m * K + kbase);
        } else {
          const float* src = A + (size_t)m * K;
          float t0 = (kbase + 0 < K) ? src[kbase + 0] : 0.f;
          float t1 = (kbase + 1 < K) ? src[kbase + 1] : 0.f;
          float t2 = (kbase + 2 < K) ? src[kbase + 2] : 0.f;
          float t3 = (kbase + 3 < K) ? src[kbase + 3] : 0.f;
          v = make_float4(t0, t1, t2, t3);
        }
      }
      As[(lk + 0) * 64 + lm] = v.x;
      As[(lk + 1) * 64 + lm] = v.y;
      As[(lk + 2) * 64 + lm] = v.z;
      As[(lk + 3) * 64 + lm] = v.w;
    }
    {
      int n = nbase + lm;
      int kbase = kk + lk;
      float4 v = make_float4(0.f, 0.f, 0.f, 0.f);
      if (n < N) {
        if (kbase + 4 <= K) {
          v = *(const float4*)(B + (size_t)n * K + kbase);
        } else {
          const float* src = B + (size_t)n * K;
          float t0 = (kbase + 0 < K) ? src[kbase + 0] : 0.f;
          float t1 = (kbase + 1 < K) ? src[kbase + 1] : 0.f;
          float t2 = (kbase + 2 < K) ? src[kbase + 2] : 0.f;
          float t3 = (kbase + 3 < K) ? src[kbase + 3] : 0.f;
          v = make_float4(t0, t1, t2, t3);
        }
      }
      Bs[(lk + 0) * 64 + lm] = v.x;
      Bs[(lk + 1) * 64 + lm] = v.y;
      Bs[(lk + 2) * 64 + lm] = v.z;
      Bs[(lk + 3) * 64 + lm] = v.w;
    }
    __syncthreads();
#pragma unroll
    for (int k = 0; k < 16; k++) {
      float4 av = *(const float4*)(As + k * 64 + (ty << 2));
      float4 bv = *(const float4*)(Bs + k * 64 + (tx << 2));
      acc[0][0] += av.x * bv.x; acc[0][1] += av.x * bv.y; acc[0][2] += av.x * bv.z; acc[0][3] += av.x * bv.w;
      acc[1][0] += av.y * bv.x; acc[1][1] += av.y * bv.y; acc[1][2] += av.y * bv.z; acc[1][3] += av.y * bv.w;
      acc[2][0] += av.z * bv.x; acc[2][1] += av.z * bv.y; acc[2][2] += av.z * bv.z; acc[2][3] += av.z * bv.w;
      acc[3][0] += av.w * bv.x; acc[3][1] += av.w * bv.y; acc[3][2] += av.w * bv.z; acc[3][3] += av.w * bv.w;
    }
    __syncthreads();
  }

#pragma unroll
  for (int i = 0; i < 4; i++) {
    int m = mbase + (ty << 2) + i;
    if (m >= M) continue;
#pragma unroll
    for (int j = 0; j < 4; j++) {
      int n = nbase + (tx << 2) + j;
      if (n >= N) continue;
      float v = acc[i][j];
      if (bias) v += bias[n];
      if (Cin) v += Cin[(size_t)m * N + n];
      C[(size_t)m * N + n] = v;
    }
  }
}

__global__ __launch_bounds__(256) void gemm_nt(
    const float* __restrict__ A, const float* __restrict__ B,
    const float* __restrict__ bias, float* __restrict__ C,
    int M, int N, int K)
{
  __shared__ float As[16 * 64];
  __shared__ float Bs[16 * 64];
  gemm_nt_body(A, B, bias, nullptr, C, M, N, K, As, Bs);
}

// ---------------------------------------------------------------------------
// Transpose 3 weight matrices (1200,300) -> (300,1200). z selects matrix.
// ---------------------------------------------------------------------------
__global__ __launch_bounds__(256) void transpose3_kernel(
    const float* __restrict__ W0, const float* __restrict__ W1,
    const float* __restrict__ W2,
    float* __restrict__ T0, float* __restrict__ T1, float* __restrict__ T2)
{
  const float* W = (blockIdx.z == 0) ? W0 : (blockIdx.z == 1) ? W1 : W2;
  float* T = (blockIdx.z == 0) ? T0 : (blockIdx.z == 1) ? T1 : T2;
  __shared__ float tile[32][33];
  const int tx = threadIdx.x & 31, ty = threadIdx.x >> 5;  // 32 x 8
  const int nb = blockIdx.x * 32, kb = blockIdx.y * 32;
#pragma unroll
  for (int i = 0; i < 4; i++) {
    int n = nb + ty + i * 8, k = kb + tx;
    if (n < 1200 && k < 300) tile[ty + i * 8][tx] = W[(size_t)n * 300 + k];
  }
  __syncthreads();
#pragma unroll
  for (int i = 0; i < 4; i++) {
    int k = kb + ty + i * 8, n = nb + tx;
    if (n < 1200 && k < 300) T[(size_t)k * 1200 + n] = tile[tx][ty + i * 8];
  }
}

// ---------------------------------------------------------------------------
// Persistent LSTM: block owns 4 batch rows, iterates all 64 timesteps.
// grid = 2*bpd blocks (first bpd = fw, rest = bw), 512 threads.
// Threads: kh = tid>>8 (K half: 150 each), tq = tid&255 (col quads).
// Quad ownership: q0 = tq (cols 4tq..4tq+3); q1 = 256+tq if tq<44.
// g layout in LDS: [kh][c][r] ; h,c layout: [k][r] (addr = k*4+r).
// ---------------------------------------------------------------------------
__global__ __launch_bounds__(512) void lstm_persistent(
    const float* __restrict__ WT0, const float* __restrict__ WT1,  // (300,1200)
    const float* __restrict__ gx0, const float* __restrict__ gx1,  // (64,NB,1200)
    float* __restrict__ hist0, float* __restrict__ hist1,          // (64,NB,300) or null
    float* __restrict__ hfin,                                      // (2,NB,300) or null
    int NB, int bpd)
{
  const int b = blockIdx.x;
  const int dirb = (b >= bpd) ? 1 : 0;
  const int n0 = (b - dirb * bpd) * 4;
  const int tid = threadIdx.x;
  const int kh = tid >> 8;
  const int tq = tid & 255;
  const bool has2 = (tq < 44);
  const int k0 = kh * 150;

  const float* WT = dirb ? WT1 : WT0;
  const float* gx = dirb ? gx1 : gx0;
  float* hist = dirb ? hist1 : hist0;

  __shared__ float h_lds[1200];   // [k][r]
  __shared__ float c_lds[1200];
  __shared__ float g_lds[2 * 4800];  // [kh][c][r]

  for (int e = tid; e < 1200; e += 512) { h_lds[e] = 0.f; c_lds[e] = 0.f; }
  __syncthreads();

  for (int t = 0; t < 64; t++) {
    const int tg = dirb ? (63 - t) : t;
    const float* gxt = gx + ((size_t)tg * NB + n0) * 1200;

    float acc0[4][4], acc1[4][4];
    if (kh == 0) {
      // init with precomputed x-gates (added exactly once, by the kh=0 half)
#pragma unroll
      for (int r = 0; r < 4; r++) {
        float4 v = *(const float4*)(gxt + (size_t)r * 1200 + 4 * tq);
        acc0[r][0] = v.x; acc0[r][1] = v.y; acc0[r][2] = v.z; acc0[r][3] = v.w;
      }
      if (has2) {
#pragma unroll
        for (int r = 0; r < 4; r++) {
          float4 v = *(const float4*)(gxt + (size_t)r * 1200 + 1024 + 4 * tq);
          acc1[r][0] = v.x; acc1[r][1] = v.y; acc1[r][2] = v.z; acc1[r][3] = v.w;
        }
      }
    } else {
#pragma unroll
      for (int r = 0; r < 4; r++)
#pragma unroll
        for (int j = 0; j < 4; j++) { acc0[r][j] = 0.f; acc1[r][j] = 0.f; }
    }
    if (!has2) {
#pragma unroll
      for (int r = 0; r < 4; r++)
#pragma unroll
        for (int j = 0; j < 4; j++) acc1[r][j] = 0.f;
    }

    // GEMM over this thread's K half
    {
      const float* wrow = WT + (size_t)k0 * 1200 + 4 * tq;
      const float* hrow = &h_lds[k0 * 4];
#pragma unroll 2
      for (int k = 0; k < 150; k++) {
        float4 hv = *(const float4*)hrow;         // h[k][0..3] (broadcast)
        float4 w0 = *(const float4*)wrow;
        acc0[0][0] += hv.x * w0.x; acc0[0][1] += hv.x * w0.y; acc0[0][2] += hv.x * w0.z; acc0[0][3] += hv.x * w0.w;
        acc0[1][0] += hv.y * w0.x; acc0[1][1] += hv.y * w0.y; acc0[1][2] += hv.y * w0.z; acc0[1][3] += hv.y * w0.w;
        acc0[2][0] += hv.z * w0.x; acc0[2][1] += hv.z * w0.y; acc0[2][2] += hv.z * w0.z; acc0[2][3] += hv.z * w0.w;
        acc0[3][0] += hv.w * w0.x; acc0[3][1] += hv.w * w0.y; acc0[3][2] += hv.w * w0.z; acc0[3][3] += hv.w * w0.w;
        if (has2) {
          float4 w1 = *(const float4*)(wrow + 1024);
          acc1[0][0] += hv.x * w1.x; acc1[0][1] += hv.x * w1.y; acc1[0][2] += hv.x * w1.z; acc1[0][3] += hv.x * w1.w;
          acc1[1][0] += hv.y * w1.x; acc1[1][1] += hv.y * w1.y; acc1[1][2] += hv.y * w1.z; acc1[1][3] += hv.y * w1.w;
          acc1[2][0] += hv.z * w1.x; acc1[2][1] += hv.z * w1.y; acc1[2][2] += hv.z * w1.z; acc1[2][3] += hv.z * w1.w;
          acc1[3][0] += hv.w * w1.x; acc1[3][1] += hv.w * w1.y; acc1[3][2] += hv.w * w1.z; acc1[3][3] += hv.w * w1.w;
        }
        wrow += 1200;
        hrow += 4;
      }
    }

    // write partials to LDS: g[kh][c][r]
    {
      float* gp = g_lds + kh * 4800;
#pragma unroll
      for (int j = 0; j < 4; j++) {
        float4 v = make_float4(acc0[0][j], acc0[1][j], acc0[2][j], acc0[3][j]);
        *(float4*)&gp[(4 * tq + j) * 4] = v;
      }
      if (has2) {
#pragma unroll
        for (int j = 0; j < 4; j++) {
          float4 v = make_float4(acc1[0][j], acc1[1][j], acc1[2][j], acc1[3][j]);
          *(float4*)&gp[(1024 + 4 * tq + j) * 4] = v;
        }
      }
    }
    __syncthreads();

    // elementwise gate update: 1200 (r,k) pairs
    for (int idx = tid; idx < 1200; idx += 512) {
      const int r = idx & 3, k = idx >> 2;
      float gi = g_lds[k * 4 + r]          + g_lds[4800 + k * 4 + r];
      float gf = g_lds[(300 + k) * 4 + r]  + g_lds[4800 + (300 + k) * 4 + r];
      float gg = g_lds[(600 + k) * 4 + r]  + g_lds[4800 + (600 + k) * 4 + r];
      float go = g_lds[(900 + k) * 4 + r]  + g_lds[4800 + (900 + k) * 4 + r];
      float si = 1.f / (1.f + expf(-gi));
      float sf = 1.f / (1.f + expf(-gf));
      float so = 1.f / (1.f + expf(-go));
      float c = sf * c_lds[idx] + si * tanhf(gg);
      float h = so * tanhf(c);
      c_lds[idx] = c;
      h_lds[idx] = h;
      if (hist) hist[((size_t)tg * NB + n0 + r) * 300 + k] = h;
    }
    __syncthreads();
  }

  if (hfin) {
    for (int idx = tid; idx < 1200; idx += 512) {
      const int r = idx & 3, k = idx >> 2;
      hfin[((size_t)dirb * NB + n0 + r) * 300 + k] = h_lds[idx];
    }
  }
}

// ---------------------------------------------------------------------------
__global__ void embed_kernel(
    const int* __restrict__ prem, const int* __restrict__ hyp,
    const float* __restrict__ embW, float* __restrict__ comb)
{
  size_t i = (size_t)blockIdx.x * 256 + threadIdx.x;
  if (i >= (size_t)64 * 256 * 75) return;
  int d4 = (int)(i % 75);
  size_t r = i / 75;
  int n = (int)(r % 256);
  int t = (int)(r / 256);
  int id = (n < 128) ? prem[t * 128 + n] : hyp[t * 128 + (n - 128)];
  float4 v = *(const float4*)(embW + (size_t)id * 300 + d4 * 4);
  *(float4*)(comb + ((size_t)t * 256 + n) * 300 + d4 * 4) = v;
}

// ---------------------------------------------------------------------------
// norm4: weighted norms for all four W sets per (dir,t,n,l) + plain row norms.
// ---------------------------------------------------------------------------
__global__ __launch_bounds__(320) void norm4_kernel(
    const float* __restrict__ hs_fw, const float* __restrict__ hs_bw,
    const float* __restrict__ mp_W,
    float* __restrict__ nm4, float* __restrict__ pnorm)
{
  const int t = blockIdx.x, n = blockIdx.y, dir = blockIdx.z;
  const float* HS = dir ? hs_bw : hs_fw;
  const float* row = HS + ((size_t)t * 256 + n) * 300;
  __shared__ float sh[300];
  const int tid = threadIdx.x, g = tid >> 4, lane = tid & 15;
  for (int k = tid; k < 300; k += 320) sh[k] = row[k];
  __syncthreads();
  if (g == 0) {
    float s2 = 0.f;
    for (int k = lane; k < 300; k += 16) { float x = sh[k]; s2 += x * x; }
    for (int o = 8; o; o >>= 1) s2 += __shfl_down(s2, o, 16);
    if (lane == 0) pnorm[((size_t)dir * 64 + t) * 256 + n] = sqrtf(s2);
  }
#pragma unroll
  for (int wset = 0; wset < 4; wset++) {
    const float* W = mp_W + dir * 24000 + wset * 6000 + g * 300;
    float s1 = 0.f;
    for (int k = lane; k < 300; k += 16) {
      float x = sh[k];
      float w = W[k];
      s1 += x * x * w * w;
    }
    for (int o = 8; o; o >>= 1) s1 += __shfl_down(s1, o, 16);
    if (lane == 0)
      nm4[((((size_t)dir * 4 + wset) * 64 + t) * 256 + n) * 20 + g] = sqrtf(s1);
  }
}

// ---------------------------------------------------------------------------
// att: per (b,z), att[64,64] cosine GEMM -> normalized w (watt) + argmax idx.
// ---------------------------------------------------------------------------
__global__ __launch_bounds__(256) void att_kernel(
    const float* __restrict__ hs_fw, const float* __restrict__ hs_bw,
    const float* __restrict__ pnorm,
    float* __restrict__ watt, int* __restrict__ idxbuf)
{
  const int b = blockIdx.x, z = blockIdx.y;
  const int dir = z & 1;
  const float* HS = dir ? hs_bw : hs_fw;
  const int p_n = (z < 2) ? b : 128 + b;
  const int h_n = (z < 2) ? 128 + b : b;
  const float* pnD = pnorm + (size_t)dir * 16384;

  __shared__ float pch[64 * 100];
  __shared__ float hch[64 * 100];
  __shared__ float att[64 * 65];
  __shared__ float winv_sh[64];

  const int tid = threadIdx.x;
  const int i = tid >> 4, j = tid & 15;
  float acc[4][4];
#pragma unroll
  for (int a = 0; a < 4; a++)
#pragma unroll
    for (int c = 0; c < 4; c++) acc[a][c] = 0.f;

  for (int kc = 0; kc < 300; kc += 100) {
    for (int e = tid; e < 1600; e += 256) {
      int row = e / 25, kq = e - row * 25;
      float4 v = *(const float4*)(HS + ((size_t)row * 256 + p_n) * 300 + kc + kq * 4);
      *(float4*)&pch[row * 100 + kq * 4] = v;
      float4 w = *(const float4*)(HS + ((size_t)row * 256 + h_n) * 300 + kc + kq * 4);
      *(float4*)&hch[row * 100 + kq * 4] = w;
    }
    __syncthreads();
#pragma unroll 5
    for (int kq = 0; kq < 25; kq++) {
      float4 av[4], bv[4];
#pragma unroll
      for (int a = 0; a < 4; a++) av[a] = *(const float4*)&pch[(i + 16 * a) * 100 + kq * 4];
#pragma unroll
      for (int c = 0; c < 4; c++) bv[c] = *(const float4*)&hch[(j + 16 * c) * 100 + kq * 4];
#pragma unroll
      for (int a = 0; a < 4; a++)
#pragma unroll
        for (int c = 0; c < 4; c++)
          acc[a][c] += av[a].x * bv[c].x + av[a].y * bv[c].y + av[a].z * bv[c].z + av[a].w * bv[c].w;
    }
    __syncthreads();
  }

#pragma unroll
  for (int a = 0; a < 4; a++) {
    int t = i + 16 * a;
    float pn = pnD[t * 256 + p_n] + EPSF;
#pragma unroll
    for (int c = 0; c < 4; c++) {
      int s = j + 16 * c;
      float hn = pnD[s * 256 + h_n] + EPSF;
      att[t * 65 + s] = acc[a][c] / (pn * hn);
    }
  }
  __syncthreads();
  if (tid < 64) {
    int t = tid;
    float ssum = 0.f, mx = -1e30f; int mi = 0;
    for (int s = 0; s < 64; s++) {
      float a = att[t * 65 + s];
      ssum += a;
      if (a > mx) { mx = a; mi = s; }
    }
    winv_sh[t] = 1.f / (ssum + EPSF);
    idxbuf[((size_t)z * 128 + b) * 64 + t] = mi;
  }
  __syncthreads();
  for (int e = tid; e < 4096; e += 256) {
    int t = e >> 6, s = e & 63;
    watt[((size_t)z * 128 + b) * 4096 + t * 64 + s] = att[t * 65 + s] * winv_sh[t];
  }
}

// ---------------------------------------------------------------------------
// hmean: per (b,z): hmean[t,k] = sum_s w[t,s]*h[s,k]
// ---------------------------------------------------------------------------
__global__ __launch_bounds__(256) void hmean_kernel(
    const float* __restrict__ hs_fw, const float* __restrict__ hs_bw,
    const float* __restrict__ watt, float* __restrict__ hmeanbuf)
{
  const int b = blockIdx.x, z = blockIdx.y;
  const int dir = z & 1;
  const float* HS = dir ? hs_bw : hs_fw;
  const int h_n = (z < 2) ? 128 + b : b;

  __shared__ float wsh[64 * 65];
  __shared__ float hch[64 * 128];

  const int tid = threadIdx.x;
  const int ti = tid >> 4, kj = tid & 15;
  const float* wsrc = watt + ((size_t)z * 128 + b) * 4096;
  for (int e = tid; e < 4096; e += 256) {
    int t = e >> 6, s = e & 63;
    wsh[t * 65 + s] = wsrc[t * 64 + s];
  }

  for (int kbase = 0; kbase < 300; kbase += 128) {
    int kw = min(128, 300 - kbase);
    int nf4 = kw >> 2;  // 32,32,11
    __syncthreads();
    for (int e = tid; e < 64 * nf4; e += 256) {
      int row = e / nf4, q = e - row * nf4;
      float4 v = *(const float4*)(HS + ((size_t)row * 256 + h_n) * 300 + kbase + q * 4);
      *(float4*)&hch[row * 128 + q * 4] = v;
    }
    __syncthreads();
    float acc[4][8];
#pragma unroll
    for (int a = 0; a < 4; a++)
#pragma unroll
      for (int c = 0; c < 8; c++) acc[a][c] = 0.f;
    for (int s = 0; s < 64; s++) {
      float4 h0 = *(const float4*)&hch[s * 128 + 4 * kj];
      float4 h1 = *(const float4*)&hch[s * 128 + 4 * (kj + 16)];
#pragma unroll
      for (int a = 0; a < 4; a++) {
        float w = wsh[(4 * ti + a) * 65 + s];
        acc[a][0] += w * h0.x; acc[a][1] += w * h0.y; acc[a][2] += w * h0.z; acc[a][3] += w * h0.w;
        acc[a][4] += w * h1.x; acc[a][5] += w * h1.y; acc[a][6] += w * h1.z; acc[a][7] += w * h1.w;
      }
    }
#pragma unroll
    for (int a = 0; a < 4; a++) {
      int t = 4 * ti + a;
#pragma unroll
      for (int c = 0; c < 2; c++) {
        int kq = kj + 16 * c;
        if (kq * 4 < kw) {
          int k = kbase + kq * 4;
          float4 v = make_float4(acc[a][4 * c], acc[a][4 * c + 1], acc[a][4 * c + 2], acc[a][4 * c + 3]);
          *(float4*)&hmeanbuf[(((size_t)z * 128 + b) * 64 + t) * 300 + k] = v;
        }
      }
    }
  }
}

// ---------------------------------------------------------------------------
// maxp: per (b,z,tt): num[t,s,l] GEMM with register tiles, fused max over s.
// ---------------------------------------------------------------------------
__global__ __launch_bounds__(128) void maxp_kernel(
    const float* __restrict__ hs_fw, const float* __restrict__ hs_bw,
    const float* __restrict__ mp_W, const float* __restrict__ nm4,
    float* __restrict__ m_out)
{
  const int b = blockIdx.x, z = blockIdx.y, tt = blockIdx.z;
  const int dir = z & 1;
  const float* HS = dir ? hs_bw : hs_fw;
  const int p_n = (z < 2) ? b : 128 + b;
  const int h_n = (z < 2) ? 128 + b : b;
  const int t_base = tt * 8;
  const float* Wm = mp_W + dir * 24000 + 6000;

  __shared__ float psh[8 * 100];
  __shared__ float hsh[64 * 100];
  __shared__ float wsh[20 * 100];

  const int tid = threadIdx.x;
  const int t_loc = tid >> 4;
  const int sg = (tid >> 1) & 7;
  const int lg = tid & 1;
  const int t = t_base + t_loc;

  float acc[8][10];
#pragma unroll
  for (int i = 0; i < 8; i++)
#pragma unroll
    for (int j = 0; j < 10; j++) acc[i][j] = 0.f;

  for (int kc = 0; kc < 300; kc += 100) {
    for (int e = tid; e < 200; e += 128) {
      int row = e / 25, q = e - row * 25;
      float4 v = *(const float4*)(HS + ((size_t)(t_base + row) * 256 + p_n) * 300 + kc + q * 4);
      *(float4*)&psh[row * 100 + q * 4] = v;
    }
    for (int e = tid; e < 1600; e += 128) {
      int row = e / 25, q = e - row * 25;
      float4 v = *(const float4*)(HS + ((size_t)row * 256 + h_n) * 300 + kc + q * 4);
      *(float4*)&hsh[row * 100 + q * 4] = v;
    }
    for (int e = tid; e < 500; e += 128) {
      int row = e / 25, q = e - row * 25;
      float4 w = *(const float4*)(Wm + (size_t)row * 300 + kc + q * 4);
      w.x *= w.x; w.y *= w.y; w.z *= w.z; w.w *= w.w;
      *(float4*)&wsh[row * 100 + q * 4] = w;
    }
    __syncthreads();
    for (int kq = 0; kq < 25; kq++) {
      float4 pv = *(const float4*)&psh[t_loc * 100 + kq * 4];
      float4 hv[8];
#pragma unroll
      for (int i = 0; i < 8; i++) hv[i] = *(const float4*)&hsh[(sg + 8 * i) * 100 + kq * 4];
#pragma unroll
      for (int j = 0; j < 10; j++) {
        float4 wv = *(const float4*)&wsh[(lg * 10 + j) * 100 + kq * 4];
        float pwx = pv.x * wv.x, pwy = pv.y * wv.y, pwz = pv.z * wv.z, pww = pv.w * wv.w;
#pragma unroll
        for (int i = 0; i < 8; i++)
          acc[i][j] += hv[i].x * pwx + hv[i].y * pwy + hv[i].z * pwz + hv[i].w * pww;
      }
    }
    __syncthreads();
  }

  const float* nmD = nm4 + ((size_t)dir * 4 + 1) * 327680;
  float pn[10], rmax[10];
#pragma unroll
  for (int j = 0; j < 10; j++) {
    pn[j] = nmD[((size_t)t * 256 + p_n) * 20 + lg * 10 + j];
    rmax[j] = -1e30f;
  }
#pragma unroll
  for (int i = 0; i < 8; i++) {
    int s = sg + 8 * i;
#pragma unroll
    for (int j = 0; j < 10; j++) {
      float hn = nmD[((size_t)s * 256 + h_n) * 20 + lg * 10 + j];
      float r = acc[i][j] / (pn[j] * hn + EPSF);
      rmax[j] = fmaxf(rmax[j], r);
    }
  }
#pragma unroll
  for (int off = 8; off >= 2; off >>= 1)
#pragma unroll
    for (int j = 0; j < 10; j++)
      rmax[j] = fmaxf(rmax[j], __shfl_down(rmax[j], off));
  if (sg == 0) {
    float* mrow = m_out + ((size_t)t * 128 + b) * 320 + z * 80;
#pragma unroll
    for (int j = 0; j < 10; j++) mrow[20 + lg * 10 + j] = rmax[j];
  }
}

// ---------------------------------------------------------------------------
// rest: per (b,z): full / attm / maxattm for all t. W^2 staged once in LDS.
// ---------------------------------------------------------------------------
__global__ __launch_bounds__(320) void rest_kernel(
    const float* __restrict__ hs_fw, const float* __restrict__ hs_bw,
    const float* __restrict__ mp_W, const float* __restrict__ nm4,
    const float* __restrict__ hmeanbuf, const int* __restrict__ idxbuf,
    float* __restrict__ m_out)
{
  const int b = blockIdx.x, z = blockIdx.y;
  const int dir = z & 1;
  const float* HS = dir ? hs_bw : hs_fw;
  const int p_n = (z < 2) ? b : 128 + b;
  const int h_n = (z < 2) ? 128 + b : b;
  const int v_t = dir ? 0 : 63;

  __shared__ float w2f[6000], w2a[6000], w2m[6000];
  __shared__ float vsh[300], psh[300], hmsh[300], hxsh[300];

  const int tid = threadIdx.x;
  const int g = tid >> 4, lane = tid & 15;
  const float* Wf = mp_W + dir * 24000;
  const float* Wa = Wf + 12000;
  const float* Wma = Wf + 18000;
  for (int e = tid; e < 6000; e += 320) {
    float a = Wf[e], bb = Wa[e], c = Wma[e];
    w2f[e] = a * a; w2a[e] = bb * bb; w2m[e] = c * c;
  }
  for (int e = tid; e < 300; e += 320)
    vsh[e] = HS[((size_t)v_t * 256 + h_n) * 300 + e];
  __syncthreads();

  const float* base0 = nm4 + ((size_t)dir * 4 + 0) * 327680;
  const float* base2 = nm4 + ((size_t)dir * 4 + 2) * 327680;
  const float* base3 = nm4 + ((size_t)dir * 4 + 3) * 327680;
  const float vnf = base0[((size_t)v_t * 256 + h_n) * 20 + g];

  for (int t = 0; t < 64; t++) {
    int idx = idxbuf[((size_t)z * 128 + b) * 64 + t];
    __syncthreads();
    for (int e = tid; e < 300; e += 320) {
      psh[e] = HS[((size_t)t * 256 + p_n) * 300 + e];
      hmsh[e] = hmeanbuf[(((size_t)z * 128 + b) * 64 + t) * 300 + e];
      hxsh[e] = HS[((size_t)idx * 256 + h_n) * 300 + e];
    }
    __syncthreads();
    float nf = 0.f, na = 0.f, qa = 0.f, nm = 0.f;
#pragma unroll
    for (int c = 0; c < 5; c++) {
      int k4 = lane + 16 * c;
      if (k4 < 75) {
        float4 p = *(const float4*)&psh[4 * k4];
        float4 v = *(const float4*)&vsh[4 * k4];
        float4 hm = *(const float4*)&hmsh[4 * k4];
        float4 hx = *(const float4*)&hxsh[4 * k4];
        float4 wf = *(const float4*)&w2f[g * 300 + 4 * k4];
        float4 wa = *(const float4*)&w2a[g * 300 + 4 * k4];
        float4 wm = *(const float4*)&w2m[g * 300 + 4 * k4];
        nf += p.x * v.x * wf.x + p.y * v.y * wf.y + p.z * v.z * wf.z + p.w * v.w * wf.w;
        na += p.x * hm.x * wa.x + p.y * hm.y * wa.y + p.z * hm.z * wa.z + p.w * hm.w * wa.w;
        qa += hm.x * hm.x * wa.x + hm.y * hm.y * wa.y + hm.z * hm.z * wa.z + hm.w * hm.w * wa.w;
        nm += p.x * hx.x * wm.x + p.y * hx.y * wm.y + p.z * hx.z * wm.z + p.w * hx.w * wm.w;
      }
    }
#pragma unroll
    for (int o = 8; o; o >>= 1) {
      nf += __shfl_down(nf, o);
      na += __shfl_down(na, o);
      qa += __shfl_down(qa, o);
      nm += __shfl_down(nm, o);
    }
    if (lane == 0) {
      float pnf = base0[((size_t)t * 256 + p_n) * 20 + g];
      float pna = base2[((size_t)t * 256 + p_n) * 20 + g];
      float pnm = base3[((size_t)t * 256 + p_n) * 20 + g];
      float qnm = base3[((size_t)idx * 256 + h_n) * 20 + g];
      float* mrow = m_out + ((size_t)t * 128 + b) * 320 + z * 80;
      mrow[g] = nf / (pnf * vnf + EPSF);
      mrow[40 + g] = na / (pna * sqrtf(qa) + EPSF);
      mrow[60 + g] = nm / (pnm * qnm + EPSF);
    }
  }
}

// ---------------------------------------------------------------------------
__global__ __launch_bounds__(256) void mlp_kernel(
    const float* __restrict__ shA0, const float* __restrict__ shA1,
    const float* __restrict__ bnG, const float* __restrict__ bnB,
    const float* __restrict__ W1, const float* __restrict__ b1,
    const float* __restrict__ W2, const float* __restrict__ b2,
    const float* __restrict__ outW, const float* __restrict__ outb,
    float* __restrict__ out)
{
  const int b = blockIdx.x;
  const int tid = threadIdx.x;
  __shared__ float x0[600], x1[600];
  const float inv = 1.0f / sqrtf(1.0f + 1e-5f);
  for (int j = tid; j < 600; j += 256) {
    float v = (j < 300) ? shA0[b * 300 + j] : shA1[b * 300 + (j - 300)];
    x0[j] = bnG[j] * v * inv + bnB[j];
  }
  __syncthreads();
  for (int j = tid; j < 600; j += 256) {
    float acc = b1[j];
    const float* w = W1 + (size_t)j * 600;
    for (int k = 0; k < 600; k++) acc += x0[k] * w[k];
    float r = fmaxf(acc, 0.f);
    x1[j] = bnG[600 + j] * r * inv + bnB[600 + j];
  }
  __syncthreads();
  for (int j = tid; j < 600; j += 256) {
    float acc = b2[j];
    const float* w = W2 + (size_t)j * 600;
    for (int k = 0; k < 600; k++) acc += x1[k] * w[k];
    float r = fmaxf(acc, 0.f);
    x0[j] = bnG[1200 + j] * r * inv + bnB[1200 + j];
  }
  __syncthreads();
  if (tid < 3) {
    float acc = outb[tid];
    const float* w = outW + tid * 600;
    for (int k = 0; k < 600; k++) acc += x0[k] * w[k];
    out[b * 3 + tid] = acc;
  }
}

// ---------------------------------------------------------------------------
extern "C" void kernel_launch(void* const* d_in, const int* in_sizes, int n_in,
                              void* d_out, int out_size, void* d_ws, size_t ws_size,
                              hipStream_t stream) {
  const int* premise = (const int*)d_in[0];
  const int* hypothesis = (const int*)d_in[1];
  const float* embW = (const float*)d_in[2];
  const float* cWih = (const float*)d_in[3];
  const float* cWhh = (const float*)d_in[4];
  const float* cb = (const float*)d_in[5];
  const float* mpW = (const float*)d_in[6];
  const float* aWihF = (const float*)d_in[7];
  const float* aWhhF = (const float*)d_in[8];
  const float* abF = (const float*)d_in[9];
  const float* aWihB = (const float*)d_in[10];
  const float* aWhhB = (const float*)d_in[11];
  const float* abB = (const float*)d_in[12];
  const float* bnG = (const float*)d_in[13];
  const float* bnB = (const float*)d_in[14];
  const float* W1 = (const float*)d_in[15];
  const float* b1 = (const float*)d_in[16];
  const float* W2 = (const float*)d_in[17];
  const float* b2 = (const float*)d_in[18];
  const float* outW = (const float*)d_in[19];
  const float* outb = (const float*)d_in[20];
  float* out = (float*)d_out;

  float* ws = (float*)d_ws;
  // workspace layout (floats)
  float* comb  = ws + 0;           // 4,915,200  (T,256,300); WhhT overlays after ctx-gates GEMM
  float* gates = ws + 4915200;     // 19,660,800 (T,256,1200); overlaid after ctx LSTM
  float* hsfw  = ws + 24576000;    // 4,915,200
  float* hsbw  = ws + 29491200;    // 4,915,200
  float* pnorm = ws + 34406400;    // 32,768    [2][64][256]
  float* mbuf  = ws + 35094528;    // 2,621,440 (T,128,320)
  float* sha   = ws + 38023168;    // 76,800    agg final h [2][128][300]

  // WhhT overlays in comb region (comb dead after ctx-gates GEMM)
  float* WTctx = comb;             // 360,000 (300,1200)
  float* WTaf  = comb + 360000;    // 360,000
  float* WTab  = comb + 720000;    // 360,000

  // overlays inside the dead ctx-gates region (valid between ctx LSTM and agg GEMMs)
  float* watt     = gates;                 // 2,097,152 [4][128][64][64]
  float* hmeanbuf = gates + 2097152;       // 9,830,400 [4][128][64][300]
  int*   idxbuf   = (int*)(gates + 11927552); // 32,768 [4][128][64]
  float* nm4      = gates + 11960320;      // 2,621,440 [2][4][64][256][20]

  // 1) embed
  embed_kernel<<<dim3(4800), dim3(256), 0, stream>>>(premise, hypothesis, embW, comb);

  // 2) ctx input gates (consumes comb)
  gemm_nt<<<dim3(19, 256), dim3(256), 0, stream>>>(comb, cWih, cb, gates, 16384, 1200, 300);

  // 3) transpose recurrent weights into dead comb region
  transpose3_kernel<<<dim3(38, 10, 3), dim3(256), 0, stream>>>(
      cWhh, aWhhF, aWhhB, WTctx, WTaf, WTab);

  // 4) context LSTM: persistent, 128 blocks x 4 rows, all 64 steps in-kernel
  lstm_persistent<<<dim3(128), dim3(512), 0, stream>>>(
      WTctx, WTctx, gates, gates, hsfw, hsbw, nullptr, 256, 64);

  // 5) norms (all 4 W sets) + plain norms
  norm4_kernel<<<dim3(64, 256, 2), dim3(320), 0, stream>>>(hsfw, hsbw, mpW, nm4, pnorm);

  // 6) matching pipeline
  att_kernel<<<dim3(128, 4), dim3(256), 0, stream>>>(hsfw, hsbw, pnorm, watt, idxbuf);
  hmean_kernel<<<dim3(128, 4), dim3(256), 0, stream>>>(hsfw, hsbw, watt, hmeanbuf);
  maxp_kernel<<<dim3(128, 4, 8), dim3(128), 0, stream>>>(hsfw, hsbw, mpW, nm4, mbuf);
  rest_kernel<<<dim3(128, 4), dim3(320), 0, stream>>>(hsfw, hsbw, mpW, nm4, hmeanbuf, idxbuf, mbuf);

  // 7) agg input gates (overwrite gates region; overlays fully consumed)
  float* gaf = gates;
  float* gab = gates + 9830400;
  gemm_nt<<<dim3(19, 128), dim3(256), 0, stream>>>(mbuf, aWihF, abF, gaf, 8192, 1200, 320);
  gemm_nt<<<dim3(19, 128), dim3(256), 0, stream>>>(mbuf, aWihB, abB, gab, 8192, 1200, 320);

  // 8) aggregation LSTM: persistent, 64 blocks x 4 rows, only final h kept
  lstm_persistent<<<dim3(64), dim3(512), 0, stream>>>(
      WTaf, WTab, gaf, gab, nullptr, nullptr, sha, 128, 32);

  // 9) MLP head
  mlp_kernel<<<dim3(128), dim3(256), 0, stream>>>(
      sha, sha + 38400, bnG, bnB, W1, b1, W2, b2, outW, outb, out);
}

// Round 4
// 5355.118 us; speedup vs baseline: 2.4551x; 1.0269x over previous
//
#include <hip/hip_runtime.h>
#include <cstddef>
#include <cstdint>
#include <math.h>

#define EPSF 1e-8f

// Model dims (fixed): T=64, B=128, D=300, H=300, L=20, AH=300, N2=2B=256

// ---------------------------------------------------------------------------
// Generic NT GEMM: C[m,n] = bias[n] + sum_k A[m,k]*B[n,k]
// ---------------------------------------------------------------------------
__device__ __forceinline__ void gemm_nt_body(
    const float* __restrict__ A, const float* __restrict__ B,
    const float* __restrict__ bias, const float* __restrict__ Cin,
    float* __restrict__ C, int M, int N, int K,
    float* As, float* Bs)
{
  const int tid = threadIdx.x;
  const int tx = tid & 15, ty = tid >> 4;
  const int mbase = blockIdx.y << 6, nbase = blockIdx.x << 6;
  const int lm = tid >> 2;
  const int lk = (tid & 3) << 2;
  float acc[4][4];
#pragma unroll
  for (int i = 0; i < 4; i++)
#pragma unroll
    for (int j = 0; j < 4; j++) acc[i][j] = 0.f;

  for (int kk = 0; kk < K; kk += 16) {
    {
      int m = mbase + lm;
      int kbase = kk + lk;
      float4 v = make_float4(0.f, 0.f, 0.f, 0.f);
      if (m < M) {
        if (kbase + 4 <= K) {
          v = *(const float4*)(A + (size_t)m * K + kbase);
        } else {
          const float* src = A + (size_t)m * K;
          float t0 = (kbase + 0 < K) ? src[kbase + 0] : 0.f;
          float t1 = (kbase + 1 < K) ? src[kbase + 1] : 0.f;
          float t2 = (kbase + 2 < K) ? src[kbase + 2] : 0.f;
          float t3 = (kbase + 3 < K) ? src[kbase + 3] : 0.f;
          v = make_float4(t0, t1, t2, t3);
        }
      }
      As[(lk + 0) * 64 + lm] = v.x;
      As[(lk + 1) * 64 + lm] = v.y;
      As[(lk + 2) * 64 + lm] = v.z;
      As[(lk + 3) * 64 + lm] = v.w;
    }
    {
      int n = nbase + lm;
      int kbase = kk + lk;
      float4 v = make_float4(0.f, 0.f, 0.f, 0.f);
      if (n < N) {
        if (kbase + 4 <= K) {
          v = *(const float4*)(B + (size_t)n * K + kbase);
        } else {
          const float* src = B + (size_t)n * K;
          float t0 = (kbase + 0 < K) ? src[kbase + 0] : 0.f;
          float t1 = (kbase + 1 < K) ? src[kbase + 1] : 0.f;
          float t2 = (kbase + 2 < K) ? src[kbase + 2] : 0.f;
          float t3 = (kbase + 3 < K) ? src[kbase + 3] : 0.f;
          v = make_float4(t0, t1, t2, t3);
        }
      }
      Bs[(lk + 0) * 64 + lm] = v.x;
      Bs[(lk + 1) * 64 + lm] = v.y;
      Bs[(lk + 2) * 64 + lm] = v.z;
      Bs[(lk + 3) * 64 + lm] = v.w;
    }
    __syncthreads();
#pragma unroll
    for (int k = 0; k < 16; k++) {
      float4 av = *(const float4*)(As + k * 64 + (ty << 2));
      float4 bv = *(const float4*)(Bs + k * 64 + (tx << 2));
      acc[0][0] += av.x * bv.x; acc[0][1] += av.x * bv.y; acc[0][2] += av.x * bv.z; acc[0][3] += av.x * bv.w;
      acc[1][0] += av.y * bv.x; acc[1][1] += av.y * bv.y; acc[1][2] += av.y * bv.z; acc[1][3] += av.y * bv.w;
      acc[2][0] += av.z * bv.x; acc[2][1] += av.z * bv.y; acc[2][2] += av.z * bv.z; acc[2][3] += av.z * bv.w;
      acc[3][0] += av.w * bv.x; acc[3][1] += av.w * bv.y; acc[3][2] += av.w * bv.z; acc[3][3] += av.w * bv.w;
    }
    __syncthreads();
  }

#pragma unroll
  for (int i = 0; i < 4; i++) {
    int m = mbase + (ty << 2) + i;
    if (m >= M) continue;
#pragma unroll
    for (int j = 0; j < 4; j++) {
      int n = nbase + (tx << 2) + j;
      if (n >= N) continue;
      float v = acc[i][j];
      if (bias) v += bias[n];
      if (Cin) v += Cin[(size_t)m * N + n];
      C[(size_t)m * N + n] = v;
    }
  }
}

__global__ __launch_bounds__(256) void gemm_nt(
    const float* __restrict__ A, const float* __restrict__ B,
    const float* __restrict__ bias, float* __restrict__ C,
    int M, int N, int K)
{
  __shared__ float As[16 * 64];
  __shared__ float Bs[16 * 64];
  gemm_nt_body(A, B, bias, nullptr, C, M, N, K, As, Bs);
}

// ---------------------------------------------------------------------------
// Transpose 3 weight matrices (1200,300) -> (300,1200). z selects matrix.
// ---------------------------------------------------------------------------
__global__ __launch_bounds__(256) void transpose3_kernel(
    const float* __restrict__ W0, const float* __restrict__ W1,
    const float* __restrict__ W2,
    float* __restrict__ T0, float* __restrict__ T1, float* __restrict__ T2)
{
  const float* W = (blockIdx.z == 0) ? W0 : (blockIdx.z == 1) ? W1 : W2;
  float* T = (blockIdx.z == 0) ? T0 : (blockIdx.z == 1) ? T1 : T2;
  __shared__ float tile[32][33];
  const int tx = threadIdx.x & 31, ty = threadIdx.x >> 5;  // 32 x 8
  const int nb = blockIdx.x * 32, kb = blockIdx.y * 32;
#pragma unroll
  for (int i = 0; i < 4; i++) {
    int n = nb + ty + i * 8, k = kb + tx;
    if (n < 1200 && k < 300) tile[ty + i * 8][tx] = W[(size_t)n * 300 + k];
  }
  __syncthreads();
#pragma unroll
  for (int i = 0; i < 4; i++) {
    int k = kb + ty + i * 8, n = nb + tx;
    if (n < 1200 && k < 300) T[(size_t)k * 1200 + n] = tile[tx][ty + i * 8];
  }
}

// ---------------------------------------------------------------------------
// Persistent LSTM v2: block owns R batch rows of ONE direction, all 64 steps.
// grid = 2*bpd blocks (first bpd = fw), 960 threads = 3 K-splits x 320.
// Active threads (tq<300) each own col-quad 4tq..4tq+3 over K range [100kh,+100).
// 4-deep weight prefetch ring for L2 latency hiding. c-state in registers.
// LDS: h[300*R] + g[3][1200*R]  (R=4: 62.4 KB; R=2: 31.2 KB)
// ---------------------------------------------------------------------------
template<int R>
__global__ __launch_bounds__(960, 1) void lstm_persist(
    const float* __restrict__ WT0, const float* __restrict__ WT1,  // (300,1200)
    const float* __restrict__ gx0, const float* __restrict__ gx1,  // (64,NB,1200)
    float* __restrict__ hist0, float* __restrict__ hist1,          // (64,NB,300) or null
    float* __restrict__ hfin,                                      // (2,NB,300) or null
    int NB, int bpd)
{
  const int b = blockIdx.x;
  const int dirb = (b >= bpd) ? 1 : 0;
  const int n0 = (b - dirb * bpd) * R;
  const int tid = threadIdx.x;
  const int kh = tid / 320;          // 0..2
  const int tq = tid - kh * 320;     // 0..319
  const bool active = (tq < 300);
  const int k0 = kh * 100;

  const float* WT = dirb ? WT1 : WT0;
  const float* gx = dirb ? gx1 : gx0;
  float* hist = dirb ? hist1 : hist0;

  __shared__ float h_lds[300 * R];
  __shared__ float g_lds[3 * 1200 * R];

  // c-state lives in registers of the elementwise owner threads
  float c0 = 0.f, c1 = 0.f;
  const int u0 = tid, u1 = tid + 960;

  for (int e = tid; e < 300 * R; e += 960) h_lds[e] = 0.f;
  __syncthreads();

  for (int t = 0; t < 64; t++) {
    const int tg = dirb ? (63 - t) : t;

    if (active) {
      float acc[R][4];
      {
        const float* gxt = gx + ((size_t)tg * NB + n0) * 1200 + 4 * tq;
        if (kh == 0) {
#pragma unroll
          for (int r = 0; r < R; r++) {
            float4 v = *(const float4*)(gxt + (size_t)r * 1200);
            acc[r][0] = v.x; acc[r][1] = v.y; acc[r][2] = v.z; acc[r][3] = v.w;
          }
        } else {
#pragma unroll
          for (int r = 0; r < R; r++) {
            acc[r][0] = 0.f; acc[r][1] = 0.f; acc[r][2] = 0.f; acc[r][3] = 0.f;
          }
        }
      }

      const float* wp = WT + (size_t)k0 * 1200 + 4 * tq;
      float4 w[4];
#pragma unroll
      for (int j = 0; j < 4; j++) w[j] = *(const float4*)(wp + (size_t)j * 1200);

      for (int k = 0; k < 100; k += 4) {
        float4 wn[4];
        if (k + 4 < 100) {
#pragma unroll
          for (int j = 0; j < 4; j++)
            wn[j] = *(const float4*)(wp + (size_t)(k + 4 + j) * 1200);
        }
#pragma unroll
        for (int j = 0; j < 4; j++) {
          if (R == 4) {
            float4 hv = *(const float4*)&h_lds[(k0 + k + j) * 4];
            acc[0][0] += hv.x * w[j].x; acc[0][1] += hv.x * w[j].y; acc[0][2] += hv.x * w[j].z; acc[0][3] += hv.x * w[j].w;
            acc[1][0] += hv.y * w[j].x; acc[1][1] += hv.y * w[j].y; acc[1][2] += hv.y * w[j].z; acc[1][3] += hv.y * w[j].w;
            acc[2][0] += hv.z * w[j].x; acc[2][1] += hv.z * w[j].y; acc[2][2] += hv.z * w[j].z; acc[2][3] += hv.z * w[j].w;
            acc[3][0] += hv.w * w[j].x; acc[3][1] += hv.w * w[j].y; acc[3][2] += hv.w * w[j].z; acc[3][3] += hv.w * w[j].w;
          } else {
            float2 hv = *(const float2*)&h_lds[(k0 + k + j) * 2];
            acc[0][0] += hv.x * w[j].x; acc[0][1] += hv.x * w[j].y; acc[0][2] += hv.x * w[j].z; acc[0][3] += hv.x * w[j].w;
            acc[1][0] += hv.y * w[j].x; acc[1][1] += hv.y * w[j].y; acc[1][2] += hv.y * w[j].z; acc[1][3] += hv.y * w[j].w;
          }
        }
#pragma unroll
        for (int j = 0; j < 4; j++) w[j] = wn[j];
      }

      // stage partial gates: g_lds[kh][col][r]
      float* gp = g_lds + kh * 1200 * R;
#pragma unroll
      for (int j = 0; j < 4; j++) {
        if (R == 4) {
          float4 v = make_float4(acc[0][j], acc[1][j], acc[2][j], acc[3][j]);
          *(float4*)&gp[(4 * tq + j) * 4] = v;
        } else {
          float2 v = make_float2(acc[0][j], acc[1][j]);
          *(float2*)&gp[(4 * tq + j) * 2] = v;
        }
      }
    }
    __syncthreads();

    // elementwise: this thread owns units u0 (and u1 if in range)
    {
      if (u0 < 300 * R) {
        const int k = u0 / R, r = u0 - k * R;
        float gi = 0.f, gf = 0.f, gg = 0.f, go = 0.f;
#pragma unroll
        for (int s = 0; s < 3; s++) {
          const float* gp = g_lds + s * 1200 * R;
          gi += gp[k * R + r];
          gf += gp[(300 + k) * R + r];
          gg += gp[(600 + k) * R + r];
          go += gp[(900 + k) * R + r];
        }
        float si = 1.f / (1.f + expf(-gi));
        float sf = 1.f / (1.f + expf(-gf));
        float so = 1.f / (1.f + expf(-go));
        float c = sf * c0 + si * tanhf(gg);
        float h = so * tanhf(c);
        c0 = c;
        h_lds[u0] = h;
        if (hist) hist[((size_t)tg * NB + n0 + r) * 300 + k] = h;
      }
      if (u1 < 300 * R) {
        const int k = u1 / R, r = u1 - k * R;
        float gi = 0.f, gf = 0.f, gg = 0.f, go = 0.f;
#pragma unroll
        for (int s = 0; s < 3; s++) {
          const float* gp = g_lds + s * 1200 * R;
          gi += gp[k * R + r];
          gf += gp[(300 + k) * R + r];
          gg += gp[(600 + k) * R + r];
          go += gp[(900 + k) * R + r];
        }
        float si = 1.f / (1.f + expf(-gi));
        float sf = 1.f / (1.f + expf(-gf));
        float so = 1.f / (1.f + expf(-go));
        float c = sf * c1 + si * tanhf(gg);
        float h = so * tanhf(c);
        c1 = c;
        h_lds[u1] = h;
        if (hist) hist[((size_t)tg * NB + n0 + r) * 300 + k] = h;
      }
    }
    __syncthreads();
  }

  if (hfin) {
    if (u0 < 300 * R) {
      const int k = u0 / R, r = u0 - k * R;
      hfin[((size_t)dirb * NB + n0 + r) * 300 + k] = h_lds[u0];
    }
    if (u1 < 300 * R) {
      const int k = u1 / R, r = u1 - k * R;
      hfin[((size_t)dirb * NB + n0 + r) * 300 + k] = h_lds[u1];
    }
  }
}

// ---------------------------------------------------------------------------
__global__ void embed_kernel(
    const int* __restrict__ prem, const int* __restrict__ hyp,
    const float* __restrict__ embW, float* __restrict__ comb)
{
  size_t i = (size_t)blockIdx.x * 256 + threadIdx.x;
  if (i >= (size_t)64 * 256 * 75) return;
  int d4 = (int)(i % 75);
  size_t r = i / 75;
  int n = (int)(r % 256);
  int t = (int)(r / 256);
  int id = (n < 128) ? prem[t * 128 + n] : hyp[t * 128 + (n - 128)];
  float4 v = *(const float4*)(embW + (size_t)id * 300 + d4 * 4);
  *(float4*)(comb + ((size_t)t * 256 + n) * 300 + d4 * 4) = v;
}

// ---------------------------------------------------------------------------
// norm4: weighted norms for all four W sets per (dir,t,n,l) + plain row norms.
// ---------------------------------------------------------------------------
__global__ __launch_bounds__(320) void norm4_kernel(
    const float* __restrict__ hs_fw, const float* __restrict__ hs_bw,
    const float* __restrict__ mp_W,
    float* __restrict__ nm4, float* __restrict__ pnorm)
{
  const int t = blockIdx.x, n = blockIdx.y, dir = blockIdx.z;
  const float* HS = dir ? hs_bw : hs_fw;
  const float* row = HS + ((size_t)t * 256 + n) * 300;
  __shared__ float sh[300];
  const int tid = threadIdx.x, g = tid >> 4, lane = tid & 15;
  for (int k = tid; k < 300; k += 320) sh[k] = row[k];
  __syncthreads();
  if (g == 0) {
    float s2 = 0.f;
    for (int k = lane; k < 300; k += 16) { float x = sh[k]; s2 += x * x; }
    for (int o = 8; o; o >>= 1) s2 += __shfl_down(s2, o, 16);
    if (lane == 0) pnorm[((size_t)dir * 64 + t) * 256 + n] = sqrtf(s2);
  }
#pragma unroll
  for (int wset = 0; wset < 4; wset++) {
    const float* W = mp_W + dir * 24000 + wset * 6000 + g * 300;
    float s1 = 0.f;
    for (int k = lane; k < 300; k += 16) {
      float x = sh[k];
      float w = W[k];
      s1 += x * x * w * w;
    }
    for (int o = 8; o; o >>= 1) s1 += __shfl_down(s1, o, 16);
    if (lane == 0)
      nm4[((((size_t)dir * 4 + wset) * 64 + t) * 256 + n) * 20 + g] = sqrtf(s1);
  }
}

// ---------------------------------------------------------------------------
// att: per (b,z), att[64,64] cosine GEMM -> normalized w (watt) + argmax idx.
// ---------------------------------------------------------------------------
__global__ __launch_bounds__(256) void att_kernel(
    const float* __restrict__ hs_fw, const float* __restrict__ hs_bw,
    const float* __restrict__ pnorm,
    float* __restrict__ watt, int* __restrict__ idxbuf)
{
  const int b = blockIdx.x, z = blockIdx.y;
  const int dir = z & 1;
  const float* HS = dir ? hs_bw : hs_fw;
  const int p_n = (z < 2) ? b : 128 + b;
  const int h_n = (z < 2) ? 128 + b : b;
  const float* pnD = pnorm + (size_t)dir * 16384;

  __shared__ float pch[64 * 100];
  __shared__ float hch[64 * 100];
  __shared__ float att[64 * 65];
  __shared__ float winv_sh[64];

  const int tid = threadIdx.x;
  const int i = tid >> 4, j = tid & 15;
  float acc[4][4];
#pragma unroll
  for (int a = 0; a < 4; a++)
#pragma unroll
    for (int c = 0; c < 4; c++) acc[a][c] = 0.f;

  for (int kc = 0; kc < 300; kc += 100) {
    for (int e = tid; e < 1600; e += 256) {
      int row = e / 25, kq = e - row * 25;
      float4 v = *(const float4*)(HS + ((size_t)row * 256 + p_n) * 300 + kc + kq * 4);
      *(float4*)&pch[row * 100 + kq * 4] = v;
      float4 w = *(const float4*)(HS + ((size_t)row * 256 + h_n) * 300 + kc + kq * 4);
      *(float4*)&hch[row * 100 + kq * 4] = w;
    }
    __syncthreads();
#pragma unroll 5
    for (int kq = 0; kq < 25; kq++) {
      float4 av[4], bv[4];
#pragma unroll
      for (int a = 0; a < 4; a++) av[a] = *(const float4*)&pch[(i + 16 * a) * 100 + kq * 4];
#pragma unroll
      for (int c = 0; c < 4; c++) bv[c] = *(const float4*)&hch[(j + 16 * c) * 100 + kq * 4];
#pragma unroll
      for (int a = 0; a < 4; a++)
#pragma unroll
        for (int c = 0; c < 4; c++)
          acc[a][c] += av[a].x * bv[c].x + av[a].y * bv[c].y + av[a].z * bv[c].z + av[a].w * bv[c].w;
    }
    __syncthreads();
  }

#pragma unroll
  for (int a = 0; a < 4; a++) {
    int t = i + 16 * a;
    float pn = pnD[t * 256 + p_n] + EPSF;
#pragma unroll
    for (int c = 0; c < 4; c++) {
      int s = j + 16 * c;
      float hn = pnD[s * 256 + h_n] + EPSF;
      att[t * 65 + s] = acc[a][c] / (pn * hn);
    }
  }
  __syncthreads();
  if (tid < 64) {
    int t = tid;
    float ssum = 0.f, mx = -1e30f; int mi = 0;
    for (int s = 0; s < 64; s++) {
      float a = att[t * 65 + s];
      ssum += a;
      if (a > mx) { mx = a; mi = s; }
    }
    winv_sh[t] = 1.f / (ssum + EPSF);
    idxbuf[((size_t)z * 128 + b) * 64 + t] = mi;
  }
  __syncthreads();
  for (int e = tid; e < 4096; e += 256) {
    int t = e >> 6, s = e & 63;
    watt[((size_t)z * 128 + b) * 4096 + t * 64 + s] = att[t * 65 + s] * winv_sh[t];
  }
}

// ---------------------------------------------------------------------------
// hmean: per (b,z): hmean[t,k] = sum_s w[t,s]*h[s,k]
// ---------------------------------------------------------------------------
__global__ __launch_bounds__(256) void hmean_kernel(
    const float* __restrict__ hs_fw, const float* __restrict__ hs_bw,
    const float* __restrict__ watt, float* __restrict__ hmeanbuf)
{
  const int b = blockIdx.x, z = blockIdx.y;
  const int dir = z & 1;
  const float* HS = dir ? hs_bw : hs_fw;
  const int h_n = (z < 2) ? 128 + b : b;

  __shared__ float wsh[64 * 65];
  __shared__ float hch[64 * 128];

  const int tid = threadIdx.x;
  const int ti = tid >> 4, kj = tid & 15;
  const float* wsrc = watt + ((size_t)z * 128 + b) * 4096;
  for (int e = tid; e < 4096; e += 256) {
    int t = e >> 6, s = e & 63;
    wsh[t * 65 + s] = wsrc[t * 64 + s];
  }

  for (int kbase = 0; kbase < 300; kbase += 128) {
    int kw = min(128, 300 - kbase);
    int nf4 = kw >> 2;  // 32,32,11
    __syncthreads();
    for (int e = tid; e < 64 * nf4; e += 256) {
      int row = e / nf4, q = e - row * nf4;
      float4 v = *(const float4*)(HS + ((size_t)row * 256 + h_n) * 300 + kbase + q * 4);
      *(float4*)&hch[row * 128 + q * 4] = v;
    }
    __syncthreads();
    float acc[4][8];
#pragma unroll
    for (int a = 0; a < 4; a++)
#pragma unroll
      for (int c = 0; c < 8; c++) acc[a][c] = 0.f;
    for (int s = 0; s < 64; s++) {
      float4 h0 = *(const float4*)&hch[s * 128 + 4 * kj];
      float4 h1 = *(const float4*)&hch[s * 128 + 4 * (kj + 16)];
#pragma unroll
      for (int a = 0; a < 4; a++) {
        float w = wsh[(4 * ti + a) * 65 + s];
        acc[a][0] += w * h0.x; acc[a][1] += w * h0.y; acc[a][2] += w * h0.z; acc[a][3] += w * h0.w;
        acc[a][4] += w * h1.x; acc[a][5] += w * h1.y; acc[a][6] += w * h1.z; acc[a][7] += w * h1.w;
      }
    }
#pragma unroll
    for (int a = 0; a < 4; a++) {
      int t = 4 * ti + a;
#pragma unroll
      for (int c = 0; c < 2; c++) {
        int kq = kj + 16 * c;
        if (kq * 4 < kw) {
          int k = kbase + kq * 4;
          float4 v = make_float4(acc[a][4 * c], acc[a][4 * c + 1], acc[a][4 * c + 2], acc[a][4 * c + 3]);
          *(float4*)&hmeanbuf[(((size_t)z * 128 + b) * 64 + t) * 300 + k] = v;
        }
      }
    }
  }
}

// ---------------------------------------------------------------------------
// maxp: per (b,z,tt): num[t,s,l] GEMM with register tiles, fused max over s.
// ---------------------------------------------------------------------------
__global__ __launch_bounds__(128) void maxp_kernel(
    const float* __restrict__ hs_fw, const float* __restrict__ hs_bw,
    const float* __restrict__ mp_W, const float* __restrict__ nm4,
    float* __restrict__ m_out)
{
  const int b = blockIdx.x, z = blockIdx.y, tt = blockIdx.z;
  const int dir = z & 1;
  const float* HS = dir ? hs_bw : hs_fw;
  const int p_n = (z < 2) ? b : 128 + b;
  const int h_n = (z < 2) ? 128 + b : b;
  const int t_base = tt * 8;
  const float* Wm = mp_W + dir * 24000 + 6000;

  __shared__ float psh[8 * 100];
  __shared__ float hsh[64 * 100];
  __shared__ float wsh[20 * 100];

  const int tid = threadIdx.x;
  const int t_loc = tid >> 4;
  const int sg = (tid >> 1) & 7;
  const int lg = tid & 1;
  const int t = t_base + t_loc;

  float acc[8][10];
#pragma unroll
  for (int i = 0; i < 8; i++)
#pragma unroll
    for (int j = 0; j < 10; j++) acc[i][j] = 0.f;

  for (int kc = 0; kc < 300; kc += 100) {
    for (int e = tid; e < 200; e += 128) {
      int row = e / 25, q = e - row * 25;
      float4 v = *(const float4*)(HS + ((size_t)(t_base + row) * 256 + p_n) * 300 + kc + q * 4);
      *(float4*)&psh[row * 100 + q * 4] = v;
    }
    for (int e = tid; e < 1600; e += 128) {
      int row = e / 25, q = e - row * 25;
      float4 v = *(const float4*)(HS + ((size_t)row * 256 + h_n) * 300 + kc + q * 4);
      *(float4*)&hsh[row * 100 + q * 4] = v;
    }
    for (int e = tid; e < 500; e += 128) {
      int row = e / 25, q = e - row * 25;
      float4 w = *(const float4*)(Wm + (size_t)row * 300 + kc + q * 4);
      w.x *= w.x; w.y *= w.y; w.z *= w.z; w.w *= w.w;
      *(float4*)&wsh[row * 100 + q * 4] = w;
    }
    __syncthreads();
    for (int kq = 0; kq < 25; kq++) {
      float4 pv = *(const float4*)&psh[t_loc * 100 + kq * 4];
      float4 hv[8];
#pragma unroll
      for (int i = 0; i < 8; i++) hv[i] = *(const float4*)&hsh[(sg + 8 * i) * 100 + kq * 4];
#pragma unroll
      for (int j = 0; j < 10; j++) {
        float4 wv = *(const float4*)&wsh[(lg * 10 + j) * 100 + kq * 4];
        float pwx = pv.x * wv.x, pwy = pv.y * wv.y, pwz = pv.z * wv.z, pww = pv.w * wv.w;
#pragma unroll
        for (int i = 0; i < 8; i++)
          acc[i][j] += hv[i].x * pwx + hv[i].y * pwy + hv[i].z * pwz + hv[i].w * pww;
      }
    }
    __syncthreads();
  }

  const float* nmD = nm4 + ((size_t)dir * 4 + 1) * 327680;
  float pn[10], rmax[10];
#pragma unroll
  for (int j = 0; j < 10; j++) {
    pn[j] = nmD[((size_t)t * 256 + p_n) * 20 + lg * 10 + j];
    rmax[j] = -1e30f;
  }
#pragma unroll
  for (int i = 0; i < 8; i++) {
    int s = sg + 8 * i;
#pragma unroll
    for (int j = 0; j < 10; j++) {
      float hn = nmD[((size_t)s * 256 + h_n) * 20 + lg * 10 + j];
      float r = acc[i][j] / (pn[j] * hn + EPSF);
      rmax[j] = fmaxf(rmax[j], r);
    }
  }
#pragma unroll
  for (int off = 8; off >= 2; off >>= 1)
#pragma unroll
    for (int j = 0; j < 10; j++)
      rmax[j] = fmaxf(rmax[j], __shfl_down(rmax[j], off));
  if (sg == 0) {
    float* mrow = m_out + ((size_t)t * 128 + b) * 320 + z * 80;
#pragma unroll
    for (int j = 0; j < 10; j++) mrow[20 + lg * 10 + j] = rmax[j];
  }
}

// ---------------------------------------------------------------------------
// rest: per (b,z): full / attm / maxattm for all t. W^2 staged once in LDS.
// ---------------------------------------------------------------------------
__global__ __launch_bounds__(320) void rest_kernel(
    const float* __restrict__ hs_fw, const float* __restrict__ hs_bw,
    const float* __restrict__ mp_W, const float* __restrict__ nm4,
    const float* __restrict__ hmeanbuf, const int* __restrict__ idxbuf,
    float* __restrict__ m_out)
{
  const int b = blockIdx.x, z = blockIdx.y;
  const int dir = z & 1;
  const float* HS = dir ? hs_bw : hs_fw;
  const int p_n = (z < 2) ? b : 128 + b;
  const int h_n = (z < 2) ? 128 + b : b;
  const int v_t = dir ? 0 : 63;

  __shared__ float w2f[6000], w2a[6000], w2m[6000];
  __shared__ float vsh[300], psh[300], hmsh[300], hxsh[300];

  const int tid = threadIdx.x;
  const int g = tid >> 4, lane = tid & 15;
  const float* Wf = mp_W + dir * 24000;
  const float* Wa = Wf + 12000;
  const float* Wma = Wf + 18000;
  for (int e = tid; e < 6000; e += 320) {
    float a = Wf[e], bb = Wa[e], c = Wma[e];
    w2f[e] = a * a; w2a[e] = bb * bb; w2m[e] = c * c;
  }
  for (int e = tid; e < 300; e += 320)
    vsh[e] = HS[((size_t)v_t * 256 + h_n) * 300 + e];
  __syncthreads();

  const float* base0 = nm4 + ((size_t)dir * 4 + 0) * 327680;
  const float* base2 = nm4 + ((size_t)dir * 4 + 2) * 327680;
  const float* base3 = nm4 + ((size_t)dir * 4 + 3) * 327680;
  const float vnf = base0[((size_t)v_t * 256 + h_n) * 20 + g];

  for (int t = 0; t < 64; t++) {
    int idx = idxbuf[((size_t)z * 128 + b) * 64 + t];
    __syncthreads();
    for (int e = tid; e < 300; e += 320) {
      psh[e] = HS[((size_t)t * 256 + p_n) * 300 + e];
      hmsh[e] = hmeanbuf[(((size_t)z * 128 + b) * 64 + t) * 300 + e];
      hxsh[e] = HS[((size_t)idx * 256 + h_n) * 300 + e];
    }
    __syncthreads();
    float nf = 0.f, na = 0.f, qa = 0.f, nm = 0.f;
#pragma unroll
    for (int c = 0; c < 5; c++) {
      int k4 = lane + 16 * c;
      if (k4 < 75) {
        float4 p = *(const float4*)&psh[4 * k4];
        float4 v = *(const float4*)&vsh[4 * k4];
        float4 hm = *(const float4*)&hmsh[4 * k4];
        float4 hx = *(const float4*)&hxsh[4 * k4];
        float4 wf = *(const float4*)&w2f[g * 300 + 4 * k4];
        float4 wa = *(const float4*)&w2a[g * 300 + 4 * k4];
        float4 wm = *(const float4*)&w2m[g * 300 + 4 * k4];
        nf += p.x * v.x * wf.x + p.y * v.y * wf.y + p.z * v.z * wf.z + p.w * v.w * wf.w;
        na += p.x * hm.x * wa.x + p.y * hm.y * wa.y + p.z * hm.z * wa.z + p.w * hm.w * wa.w;
        qa += hm.x * hm.x * wa.x + hm.y * hm.y * wa.y + hm.z * hm.z * wa.z + hm.w * hm.w * wa.w;
        nm += p.x * hx.x * wm.x + p.y * hx.y * wm.y + p.z * hx.z * wm.z + p.w * hx.w * wm.w;
      }
    }
#pragma unroll
    for (int o = 8; o; o >>= 1) {
      nf += __shfl_down(nf, o);
      na += __shfl_down(na, o);
      qa += __shfl_down(qa, o);
      nm += __shfl_down(nm, o);
    }
    if (lane == 0) {
      float pnf = base0[((size_t)t * 256 + p_n) * 20 + g];
      float pna = base2[((size_t)t * 256 + p_n) * 20 + g];
      float pnm = base3[((size_t)t * 256 + p_n) * 20 + g];
      float qnm = base3[((size_t)idx * 256 + h_n) * 20 + g];
      float* mrow = m_out + ((size_t)t * 128 + b) * 320 + z * 80;
      mrow[g] = nf / (pnf * vnf + EPSF);
      mrow[40 + g] = na / (pna * sqrtf(qa) + EPSF);
      mrow[60 + g] = nm / (pnm * qnm + EPSF);
    }
  }
}

// ---------------------------------------------------------------------------
__global__ __launch_bounds__(256) void mlp_kernel(
    const float* __restrict__ shA0, const float* __restrict__ shA1,
    const float* __restrict__ bnG, const float* __restrict__ bnB,
    const float* __restrict__ W1, const float* __restrict__ b1,
    const float* __restrict__ W2, const float* __restrict__ b2,
    const float* __restrict__ outW, const float* __restrict__ outb,
    float* __restrict__ out)
{
  const int b = blockIdx.x;
  const int tid = threadIdx.x;
  __shared__ float x0[600], x1[600];
  const float inv = 1.0f / sqrtf(1.0f + 1e-5f);
  for (int j = tid; j < 600; j += 256) {
    float v = (j < 300) ? shA0[b * 300 + j] : shA1[b * 300 + (j - 300)];
    x0[j] = bnG[j] * v * inv + bnB[j];
  }
  __syncthreads();
  for (int j = tid; j < 600; j += 256) {
    float acc = b1[j];
    const float* w = W1 + (size_t)j * 600;
    for (int k = 0; k < 600; k++) acc += x0[k] * w[k];
    float r = fmaxf(acc, 0.f);
    x1[j] = bnG[600 + j] * r * inv + bnB[600 + j];
  }
  __syncthreads();
  for (int j = tid; j < 600; j += 256) {
    float acc = b2[j];
    const float* w = W2 + (size_t)j * 600;
    for (int k = 0; k < 600; k++) acc += x1[k] * w[k];
    float r = fmaxf(acc, 0.f);
    x0[j] = bnG[1200 + j] * r * inv + bnB[1200 + j];
  }
  __syncthreads();
  if (tid < 3) {
    float acc = outb[tid];
    const float* w = outW + tid * 600;
    for (int k = 0; k < 600; k++) acc += x0[k] * w[k];
    out[b * 3 + tid] = acc;
  }
}

// ---------------------------------------------------------------------------
extern "C" void kernel_launch(void* const* d_in, const int* in_sizes, int n_in,
                              void* d_out, int out_size, void* d_ws, size_t ws_size,
                              hipStream_t stream) {
  const int* premise = (const int*)d_in[0];
  const int* hypothesis = (const int*)d_in[1];
  const float* embW = (const float*)d_in[2];
  const float* cWih = (const float*)d_in[3];
  const float* cWhh = (const float*)d_in[4];
  const float* cb = (const float*)d_in[5];
  const float* mpW = (const float*)d_in[6];
  const float* aWihF = (const float*)d_in[7];
  const float* aWhhF = (const float*)d_in[8];
  const float* abF = (const float*)d_in[9];
  const float* aWihB = (const float*)d_in[10];
  const float* aWhhB = (const float*)d_in[11];
  const float* abB = (const float*)d_in[12];
  const float* bnG = (const float*)d_in[13];
  const float* bnB = (const float*)d_in[14];
  const float* W1 = (const float*)d_in[15];
  const float* b1 = (const float*)d_in[16];
  const float* W2 = (const float*)d_in[17];
  const float* b2 = (const float*)d_in[18];
  const float* outW = (const float*)d_in[19];
  const float* outb = (const float*)d_in[20];
  float* out = (float*)d_out;

  float* ws = (float*)d_ws;
  // workspace layout (floats)
  float* comb  = ws + 0;           // 4,915,200  (T,256,300); WhhT overlays after ctx-gates GEMM
  float* gates = ws + 4915200;     // 19,660,800 (T,256,1200); overlaid after ctx LSTM
  float* hsfw  = ws + 24576000;    // 4,915,200
  float* hsbw  = ws + 29491200;    // 4,915,200
  float* pnorm = ws + 34406400;    // 32,768    [2][64][256]
  float* mbuf  = ws + 35094528;    // 2,621,440 (T,128,320)
  float* sha   = ws + 38023168;    // 76,800    agg final h [2][128][300]

  // WhhT overlays in comb region (comb dead after ctx-gates GEMM)
  float* WTctx = comb;             // 360,000 (300,1200)
  float* WTaf  = comb + 360000;    // 360,000
  float* WTab  = comb + 720000;    // 360,000

  // overlays inside the dead ctx-gates region (valid between ctx LSTM and agg GEMMs)
  float* watt     = gates;                 // 2,097,152 [4][128][64][64]
  float* hmeanbuf = gates + 2097152;       // 9,830,400 [4][128][64][300]
  int*   idxbuf   = (int*)(gates + 11927552); // 32,768 [4][128][64]
  float* nm4      = gates + 11960320;      // 2,621,440 [2][4][64][256][20]

  // 1) embed
  embed_kernel<<<dim3(4800), dim3(256), 0, stream>>>(premise, hypothesis, embW, comb);

  // 2) ctx input gates (consumes comb)
  gemm_nt<<<dim3(19, 256), dim3(256), 0, stream>>>(comb, cWih, cb, gates, 16384, 1200, 300);

  // 3) transpose recurrent weights into dead comb region
  transpose3_kernel<<<dim3(38, 10, 3), dim3(256), 0, stream>>>(
      cWhh, aWhhF, aWhhB, WTctx, WTaf, WTab);

  // 4) context LSTM: persistent, R=4 rows/block, 128 blocks (64 fw + 64 bw)
  lstm_persist<4><<<dim3(128), dim3(960), 0, stream>>>(
      WTctx, WTctx, gates, gates, hsfw, hsbw, nullptr, 256, 64);

  // 5) norms (all 4 W sets) + plain norms
  norm4_kernel<<<dim3(64, 256, 2), dim3(320), 0, stream>>>(hsfw, hsbw, mpW, nm4, pnorm);

  // 6) matching pipeline
  att_kernel<<<dim3(128, 4), dim3(256), 0, stream>>>(hsfw, hsbw, pnorm, watt, idxbuf);
  hmean_kernel<<<dim3(128, 4), dim3(256), 0, stream>>>(hsfw, hsbw, watt, hmeanbuf);
  maxp_kernel<<<dim3(128, 4, 8), dim3(128), 0, stream>>>(hsfw, hsbw, mpW, nm4, mbuf);
  rest_kernel<<<dim3(128, 4), dim3(320), 0, stream>>>(hsfw, hsbw, mpW, nm4, hmeanbuf, idxbuf, mbuf);

  // 7) agg input gates (overwrite gates region; overlays fully consumed)
  float* gaf = gates;
  float* gab = gates + 9830400;
  gemm_nt<<<dim3(19, 128), dim3(256), 0, stream>>>(mbuf, aWihF, abF, gaf, 8192, 1200, 320);
  gemm_nt<<<dim3(19, 128), dim3(256), 0, stream>>>(mbuf, aWihB, abB, gab, 8192, 1200, 320);

  // 8) aggregation LSTM: persistent, R=2 rows/block, 128 blocks (64 fw + 64 bw)
  lstm_persist<2><<<dim3(128), dim3(960), 0, stream>>>(
      WTaf, WTab, gaf, gab, nullptr, nullptr, sha, 128, 64);

  // 9) MLP head
  mlp_kernel<<<dim3(128), dim3(256), 0, stream>>>(
      sha, sha + 38400, bnG, bnB, W1, b1, W2, b2, outW, outb, out);
}

// Round 5
// 3399.687 us; speedup vs baseline: 3.8672x; 1.5752x over previous
//
#include <hip/hip_runtime.h>
#include <cstddef>
#include <cstdint>
#include <math.h>

#define EPSF 1e-8f

// Model dims (fixed): T=64, B=128, D=300, H=300, L=20, AH=300, N2=2B=256

// ---------------------------------------------------------------------------
// 128x128 NT GEMM, 8x8 micro, KT=16: C[m,n] = bias[n] + sum_k A[m,k]*B[n,k]
// A: (M,K) rm, B: (N,K) rm. Requires N % 4 == 0.
// ---------------------------------------------------------------------------
__global__ __launch_bounds__(256) void gemm_nt128(
    const float* __restrict__ A, const float* __restrict__ B,
    const float* __restrict__ bias, float* __restrict__ C,
    int M, int N, int K)
{
  __shared__ float As[16][128];
  __shared__ float Bs[16][128];
  const int tid = threadIdx.x;
  const int tx = tid & 15, ty = tid >> 4;
  const int mbase = blockIdx.y << 7, nbase = blockIdx.x << 7;
  const int lm = tid >> 1;          // 0..127
  const int lk = (tid & 1) << 3;    // 0 or 8
  float acc[8][8];
#pragma unroll
  for (int i = 0; i < 8; i++)
#pragma unroll
    for (int j = 0; j < 8; j++) acc[i][j] = 0.f;

  for (int kk = 0; kk < K; kk += 16) {
    {
      int m = mbase + lm;
      const float* src = A + (size_t)m * K;
#pragma unroll
      for (int q = 0; q < 2; q++) {
        int kb = kk + lk + q * 4;
        float4 v = make_float4(0.f, 0.f, 0.f, 0.f);
        if (m < M) {
          if (kb + 4 <= K) {
            v = *(const float4*)(src + kb);
          } else {
            v.x = (kb + 0 < K) ? src[kb + 0] : 0.f;
            v.y = (kb + 1 < K) ? src[kb + 1] : 0.f;
            v.z = (kb + 2 < K) ? src[kb + 2] : 0.f;
            v.w = (kb + 3 < K) ? src[kb + 3] : 0.f;
          }
        }
        As[lk + q * 4 + 0][lm] = v.x;
        As[lk + q * 4 + 1][lm] = v.y;
        As[lk + q * 4 + 2][lm] = v.z;
        As[lk + q * 4 + 3][lm] = v.w;
      }
    }
    {
      int n = nbase + lm;
      const float* src = B + (size_t)n * K;
#pragma unroll
      for (int q = 0; q < 2; q++) {
        int kb = kk + lk + q * 4;
        float4 v = make_float4(0.f, 0.f, 0.f, 0.f);
        if (n < N) {
          if (kb + 4 <= K) {
            v = *(const float4*)(src + kb);
          } else {
            v.x = (kb + 0 < K) ? src[kb + 0] : 0.f;
            v.y = (kb + 1 < K) ? src[kb + 1] : 0.f;
            v.z = (kb + 2 < K) ? src[kb + 2] : 0.f;
            v.w = (kb + 3 < K) ? src[kb + 3] : 0.f;
          }
        }
        Bs[lk + q * 4 + 0][lm] = v.x;
        Bs[lk + q * 4 + 1][lm] = v.y;
        Bs[lk + q * 4 + 2][lm] = v.z;
        Bs[lk + q * 4 + 3][lm] = v.w;
      }
    }
    __syncthreads();
#pragma unroll
    for (int k = 0; k < 16; k++) {
      float4 a0 = *(const float4*)&As[k][ty * 8];
      float4 a1 = *(const float4*)&As[k][ty * 8 + 4];
      float4 b0 = *(const float4*)&Bs[k][tx * 8];
      float4 b1 = *(const float4*)&Bs[k][tx * 8 + 4];
      float av[8] = {a0.x, a0.y, a0.z, a0.w, a1.x, a1.y, a1.z, a1.w};
      float bv[8] = {b0.x, b0.y, b0.z, b0.w, b1.x, b1.y, b1.z, b1.w};
#pragma unroll
      for (int i = 0; i < 8; i++)
#pragma unroll
        for (int j = 0; j < 8; j++) acc[i][j] += av[i] * bv[j];
    }
    __syncthreads();
  }

#pragma unroll
  for (int i = 0; i < 8; i++) {
    int m = mbase + ty * 8 + i;
    if (m >= M) continue;
#pragma unroll
    for (int jq = 0; jq < 2; jq++) {
      int n = nbase + tx * 8 + jq * 4;
      if (n >= N) continue;  // N % 4 == 0 so whole quad valid when n < N
      float4 v = make_float4(acc[i][jq * 4], acc[i][jq * 4 + 1],
                             acc[i][jq * 4 + 2], acc[i][jq * 4 + 3]);
      if (bias) {
        v.x += bias[n]; v.y += bias[n + 1]; v.z += bias[n + 2]; v.w += bias[n + 3];
      }
      *(float4*)(C + (size_t)m * N + n) = v;
    }
  }
}

// ---------------------------------------------------------------------------
// Transpose 3 weight matrices (1200,300) -> (300,1200). z selects matrix.
// ---------------------------------------------------------------------------
__global__ __launch_bounds__(256) void transpose3_kernel(
    const float* __restrict__ W0, const float* __restrict__ W1,
    const float* __restrict__ W2,
    float* __restrict__ T0, float* __restrict__ T1, float* __restrict__ T2)
{
  const float* W = (blockIdx.z == 0) ? W0 : (blockIdx.z == 1) ? W1 : W2;
  float* T = (blockIdx.z == 0) ? T0 : (blockIdx.z == 1) ? T1 : T2;
  __shared__ float tile[32][33];
  const int tx = threadIdx.x & 31, ty = threadIdx.x >> 5;  // 32 x 8
  const int nb = blockIdx.x * 32, kb = blockIdx.y * 32;
#pragma unroll
  for (int i = 0; i < 4; i++) {
    int n = nb + ty + i * 8, k = kb + tx;
    if (n < 1200 && k < 300) tile[ty + i * 8][tx] = W[(size_t)n * 300 + k];
  }
  __syncthreads();
#pragma unroll
  for (int i = 0; i < 4; i++) {
    int k = kb + ty + i * 8, n = nb + tx;
    if (n < 1200 && k < 300) T[(size_t)k * 1200 + n] = tile[tx][ty + i * 8];
  }
}

// ---------------------------------------------------------------------------
// Persistent LSTM: block owns R batch rows of ONE direction, all 64 steps.
// XCD-partitioned mapping: block b -> xcd = b&7 (HW round-robin), grp = b>>3.
//   dir = xcd>>2  (XCDs 0-3 fw, 4-7 bw => per-XCD weight working set = 1 matrix)
//   row-group = grp*4 + (xcd&3)
// 960 threads = 3 K-splits x 320; active threads (tq<300) own col-quad 4tq..4tq+3.
// 4-deep weight prefetch ring; c-state in registers.
// LDS: h[300*R] + g[3][1200*R]  (R=4: 62.4 KB; R=2: 31.2 KB)
// ---------------------------------------------------------------------------
template<int R>
__global__ __launch_bounds__(960, 1) void lstm_persist(
    const float* __restrict__ WT0, const float* __restrict__ WT1,  // (300,1200)
    const float* __restrict__ gx0, const float* __restrict__ gx1,  // (64,NB,1200)
    float* __restrict__ hist0, float* __restrict__ hist1,          // (64,NB,300) or null
    float* __restrict__ hfin,                                      // (2,NB,300) or null
    int NB)
{
  const int b = blockIdx.x;
  const int xcd = b & 7;
  const int grp = b >> 3;
  const int dirb = xcd >> 2;
  const int n0 = (grp * 4 + (xcd & 3)) * R;
  const int tid = threadIdx.x;
  const int kh = tid / 320;          // 0..2
  const int tq = tid - kh * 320;     // 0..319
  const bool active = (tq < 300);
  const int k0 = kh * 100;

  const float* WT = dirb ? WT1 : WT0;
  const float* gx = dirb ? gx1 : gx0;
  float* hist = dirb ? hist1 : hist0;

  __shared__ float h_lds[300 * R];
  __shared__ float g_lds[3 * 1200 * R];

  // c-state lives in registers of the elementwise owner threads
  float c0 = 0.f, c1 = 0.f;
  const int u0 = tid, u1 = tid + 960;

  for (int e = tid; e < 300 * R; e += 960) h_lds[e] = 0.f;
  __syncthreads();

  for (int t = 0; t < 64; t++) {
    const int tg = dirb ? (63 - t) : t;

    if (active) {
      float acc[R][4];
      {
        const float* gxt = gx + ((size_t)tg * NB + n0) * 1200 + 4 * tq;
        if (kh == 0) {
#pragma unroll
          for (int r = 0; r < R; r++) {
            float4 v = *(const float4*)(gxt + (size_t)r * 1200);
            acc[r][0] = v.x; acc[r][1] = v.y; acc[r][2] = v.z; acc[r][3] = v.w;
          }
        } else {
#pragma unroll
          for (int r = 0; r < R; r++) {
            acc[r][0] = 0.f; acc[r][1] = 0.f; acc[r][2] = 0.f; acc[r][3] = 0.f;
          }
        }
      }

      const float* wp = WT + (size_t)k0 * 1200 + 4 * tq;
      float4 w[4];
#pragma unroll
      for (int j = 0; j < 4; j++) w[j] = *(const float4*)(wp + (size_t)j * 1200);

      for (int k = 0; k < 100; k += 4) {
        float4 wn[4];
        if (k + 4 < 100) {
#pragma unroll
          for (int j = 0; j < 4; j++)
            wn[j] = *(const float4*)(wp + (size_t)(k + 4 + j) * 1200);
        }
#pragma unroll
        for (int j = 0; j < 4; j++) {
          if (R == 4) {
            float4 hv = *(const float4*)&h_lds[(k0 + k + j) * 4];
            acc[0][0] += hv.x * w[j].x; acc[0][1] += hv.x * w[j].y; acc[0][2] += hv.x * w[j].z; acc[0][3] += hv.x * w[j].w;
            acc[1][0] += hv.y * w[j].x; acc[1][1] += hv.y * w[j].y; acc[1][2] += hv.y * w[j].z; acc[1][3] += hv.y * w[j].w;
            acc[2][0] += hv.z * w[j].x; acc[2][1] += hv.z * w[j].y; acc[2][2] += hv.z * w[j].z; acc[2][3] += hv.z * w[j].w;
            acc[3][0] += hv.w * w[j].x; acc[3][1] += hv.w * w[j].y; acc[3][2] += hv.w * w[j].z; acc[3][3] += hv.w * w[j].w;
          } else {
            float2 hv = *(const float2*)&h_lds[(k0 + k + j) * 2];
            acc[0][0] += hv.x * w[j].x; acc[0][1] += hv.x * w[j].y; acc[0][2] += hv.x * w[j].z; acc[0][3] += hv.x * w[j].w;
            acc[1][0] += hv.y * w[j].x; acc[1][1] += hv.y * w[j].y; acc[1][2] += hv.y * w[j].z; acc[1][3] += hv.y * w[j].w;
          }
        }
#pragma unroll
        for (int j = 0; j < 4; j++) w[j] = wn[j];
      }

      // stage partial gates: g_lds[kh][col][r]
      float* gp = g_lds + kh * 1200 * R;
#pragma unroll
      for (int j = 0; j < 4; j++) {
        if (R == 4) {
          float4 v = make_float4(acc[0][j], acc[1][j], acc[2][j], acc[3][j]);
          *(float4*)&gp[(4 * tq + j) * 4] = v;
        } else {
          float2 v = make_float2(acc[0][j], acc[1][j]);
          *(float2*)&gp[(4 * tq + j) * 2] = v;
        }
      }
    }
    __syncthreads();

    // elementwise: this thread owns units u0 (and u1 if in range)
    {
      if (u0 < 300 * R) {
        const int k = u0 / R, r = u0 - k * R;
        float gi = 0.f, gf = 0.f, gg = 0.f, go = 0.f;
#pragma unroll
        for (int s = 0; s < 3; s++) {
          const float* gp = g_lds + s * 1200 * R;
          gi += gp[k * R + r];
          gf += gp[(300 + k) * R + r];
          gg += gp[(600 + k) * R + r];
          go += gp[(900 + k) * R + r];
        }
        float si = 1.f / (1.f + expf(-gi));
        float sf = 1.f / (1.f + expf(-gf));
        float so = 1.f / (1.f + expf(-go));
        float c = sf * c0 + si * tanhf(gg);
        float h = so * tanhf(c);
        c0 = c;
        h_lds[u0] = h;
        if (hist) hist[((size_t)tg * NB + n0 + r) * 300 + k] = h;
      }
      if (u1 < 300 * R) {
        const int k = u1 / R, r = u1 - k * R;
        float gi = 0.f, gf = 0.f, gg = 0.f, go = 0.f;
#pragma unroll
        for (int s = 0; s < 3; s++) {
          const float* gp = g_lds + s * 1200 * R;
          gi += gp[k * R + r];
          gf += gp[(300 + k) * R + r];
          gg += gp[(600 + k) * R + r];
          go += gp[(900 + k) * R + r];
        }
        float si = 1.f / (1.f + expf(-gi));
        float sf = 1.f / (1.f + expf(-gf));
        float so = 1.f / (1.f + expf(-go));
        float c = sf * c1 + si * tanhf(gg);
        float h = so * tanhf(c);
        c1 = c;
        h_lds[u1] = h;
        if (hist) hist[((size_t)tg * NB + n0 + r) * 300 + k] = h;
      }
    }
    __syncthreads();
  }

  if (hfin) {
    if (u0 < 300 * R) {
      const int k = u0 / R, r = u0 - k * R;
      hfin[((size_t)dirb * NB + n0 + r) * 300 + k] = h_lds[u0];
    }
    if (u1 < 300 * R) {
      const int k = u1 / R, r = u1 - k * R;
      hfin[((size_t)dirb * NB + n0 + r) * 300 + k] = h_lds[u1];
    }
  }
}

// ---------------------------------------------------------------------------
__global__ void embed_kernel(
    const int* __restrict__ prem, const int* __restrict__ hyp,
    const float* __restrict__ embW, float* __restrict__ comb)
{
  size_t i = (size_t)blockIdx.x * 256 + threadIdx.x;
  if (i >= (size_t)64 * 256 * 75) return;
  int d4 = (int)(i % 75);
  size_t r = i / 75;
  int n = (int)(r % 256);
  int t = (int)(r / 256);
  int id = (n < 128) ? prem[t * 128 + n] : hyp[t * 128 + (n - 128)];
  float4 v = *(const float4*)(embW + (size_t)id * 300 + d4 * 4);
  *(float4*)(comb + ((size_t)t * 256 + n) * 300 + d4 * 4) = v;
}

// ---------------------------------------------------------------------------
// norm4: weighted norms for all four W sets per (dir,t,n,l) + plain row norms.
// ---------------------------------------------------------------------------
__global__ __launch_bounds__(320) void norm4_kernel(
    const float* __restrict__ hs_fw, const float* __restrict__ hs_bw,
    const float* __restrict__ mp_W,
    float* __restrict__ nm4, float* __restrict__ pnorm)
{
  const int t = blockIdx.x, n = blockIdx.y, dir = blockIdx.z;
  const float* HS = dir ? hs_bw : hs_fw;
  const float* row = HS + ((size_t)t * 256 + n) * 300;
  __shared__ float sh[300];
  const int tid = threadIdx.x, g = tid >> 4, lane = tid & 15;
  for (int k = tid; k < 300; k += 320) sh[k] = row[k];
  __syncthreads();
  if (g == 0) {
    float s2 = 0.f;
    for (int k = lane; k < 300; k += 16) { float x = sh[k]; s2 += x * x; }
    for (int o = 8; o; o >>= 1) s2 += __shfl_down(s2, o, 16);
    if (lane == 0) pnorm[((size_t)dir * 64 + t) * 256 + n] = sqrtf(s2);
  }
#pragma unroll
  for (int wset = 0; wset < 4; wset++) {
    const float* W = mp_W + dir * 24000 + wset * 6000 + g * 300;
    float s1 = 0.f;
    for (int k = lane; k < 300; k += 16) {
      float x = sh[k];
      float w = W[k];
      s1 += x * x * w * w;
    }
    for (int o = 8; o; o >>= 1) s1 += __shfl_down(s1, o, 16);
    if (lane == 0)
      nm4[((((size_t)dir * 4 + wset) * 64 + t) * 256 + n) * 20 + g] = sqrtf(s1);
  }
}

// ---------------------------------------------------------------------------
// att: per (b,z), att[64,64] cosine GEMM -> normalized w (watt) + argmax idx.
// ---------------------------------------------------------------------------
__global__ __launch_bounds__(256) void att_kernel(
    const float* __restrict__ hs_fw, const float* __restrict__ hs_bw,
    const float* __restrict__ pnorm,
    float* __restrict__ watt, int* __restrict__ idxbuf)
{
  const int b = blockIdx.x, z = blockIdx.y;
  const int dir = z & 1;
  const float* HS = dir ? hs_bw : hs_fw;
  const int p_n = (z < 2) ? b : 128 + b;
  const int h_n = (z < 2) ? 128 + b : b;
  const float* pnD = pnorm + (size_t)dir * 16384;

  __shared__ float pch[64 * 100];
  __shared__ float hch[64 * 100];
  __shared__ float att[64 * 65];
  __shared__ float winv_sh[64];

  const int tid = threadIdx.x;
  const int i = tid >> 4, j = tid & 15;
  float acc[4][4];
#pragma unroll
  for (int a = 0; a < 4; a++)
#pragma unroll
    for (int c = 0; c < 4; c++) acc[a][c] = 0.f;

  for (int kc = 0; kc < 300; kc += 100) {
    for (int e = tid; e < 1600; e += 256) {
      int row = e / 25, kq = e - row * 25;
      float4 v = *(const float4*)(HS + ((size_t)row * 256 + p_n) * 300 + kc + kq * 4);
      *(float4*)&pch[row * 100 + kq * 4] = v;
      float4 w = *(const float4*)(HS + ((size_t)row * 256 + h_n) * 300 + kc + kq * 4);
      *(float4*)&hch[row * 100 + kq * 4] = w;
    }
    __syncthreads();
#pragma unroll 5
    for (int kq = 0; kq < 25; kq++) {
      float4 av[4], bv[4];
#pragma unroll
      for (int a = 0; a < 4; a++) av[a] = *(const float4*)&pch[(i + 16 * a) * 100 + kq * 4];
#pragma unroll
      for (int c = 0; c < 4; c++) bv[c] = *(const float4*)&hch[(j + 16 * c) * 100 + kq * 4];
#pragma unroll
      for (int a = 0; a < 4; a++)
#pragma unroll
        for (int c = 0; c < 4; c++)
          acc[a][c] += av[a].x * bv[c].x + av[a].y * bv[c].y + av[a].z * bv[c].z + av[a].w * bv[c].w;
    }
    __syncthreads();
  }

#pragma unroll
  for (int a = 0; a < 4; a++) {
    int t = i + 16 * a;
    float pn = pnD[t * 256 + p_n] + EPSF;
#pragma unroll
    for (int c = 0; c < 4; c++) {
      int s = j + 16 * c;
      float hn = pnD[s * 256 + h_n] + EPSF;
      att[t * 65 + s] = acc[a][c] / (pn * hn);
    }
  }
  __syncthreads();
  if (tid < 64) {
    int t = tid;
    float ssum = 0.f, mx = -1e30f; int mi = 0;
    for (int s = 0; s < 64; s++) {
      float a = att[t * 65 + s];
      ssum += a;
      if (a > mx) { mx = a; mi = s; }
    }
    winv_sh[t] = 1.f / (ssum + EPSF);
    idxbuf[((size_t)z * 128 + b) * 64 + t] = mi;
  }
  __syncthreads();
  for (int e = tid; e < 4096; e += 256) {
    int t = e >> 6, s = e & 63;
    watt[((size_t)z * 128 + b) * 4096 + t * 64 + s] = att[t * 65 + s] * winv_sh[t];
  }
}

// ---------------------------------------------------------------------------
// hmean: per (b,z): hmean[t,k] = sum_s w[t,s]*h[s,k]
// ---------------------------------------------------------------------------
__global__ __launch_bounds__(256) void hmean_kernel(
    const float* __restrict__ hs_fw, const float* __restrict__ hs_bw,
    const float* __restrict__ watt, float* __restrict__ hmeanbuf)
{
  const int b = blockIdx.x, z = blockIdx.y;
  const int dir = z & 1;
  const float* HS = dir ? hs_bw : hs_fw;
  const int h_n = (z < 2) ? 128 + b : b;

  __shared__ float wsh[64 * 65];
  __shared__ float hch[64 * 128];

  const int tid = threadIdx.x;
  const int ti = tid >> 4, kj = tid & 15;
  const float* wsrc = watt + ((size_t)z * 128 + b) * 4096;
  for (int e = tid; e < 4096; e += 256) {
    int t = e >> 6, s = e & 63;
    wsh[t * 65 + s] = wsrc[t * 64 + s];
  }

  for (int kbase = 0; kbase < 300; kbase += 128) {
    int kw = min(128, 300 - kbase);
    int nf4 = kw >> 2;  // 32,32,11
    __syncthreads();
    for (int e = tid; e < 64 * nf4; e += 256) {
      int row = e / nf4, q = e - row * nf4;
      float4 v = *(const float4*)(HS + ((size_t)row * 256 + h_n) * 300 + kbase + q * 4);
      *(float4*)&hch[row * 128 + q * 4] = v;
    }
    __syncthreads();
    float acc[4][8];
#pragma unroll
    for (int a = 0; a < 4; a++)
#pragma unroll
      for (int c = 0; c < 8; c++) acc[a][c] = 0.f;
    for (int s = 0; s < 64; s++) {
      float4 h0 = *(const float4*)&hch[s * 128 + 4 * kj];
      float4 h1 = *(const float4*)&hch[s * 128 + 4 * (kj + 16)];
#pragma unroll
      for (int a = 0; a < 4; a++) {
        float w = wsh[(4 * ti + a) * 65 + s];
        acc[a][0] += w * h0.x; acc[a][1] += w * h0.y; acc[a][2] += w * h0.z; acc[a][3] += w * h0.w;
        acc[a][4] += w * h1.x; acc[a][5] += w * h1.y; acc[a][6] += w * h1.z; acc[a][7] += w * h1.w;
      }
    }
#pragma unroll
    for (int a = 0; a < 4; a++) {
      int t = 4 * ti + a;
#pragma unroll
      for (int c = 0; c < 2; c++) {
        int kq = kj + 16 * c;
        if (kq * 4 < kw) {
          int k = kbase + kq * 4;
          float4 v = make_float4(acc[a][4 * c], acc[a][4 * c + 1], acc[a][4 * c + 2], acc[a][4 * c + 3]);
          *(float4*)&hmeanbuf[(((size_t)z * 128 + b) * 64 + t) * 300 + k] = v;
        }
      }
    }
  }
}

// ---------------------------------------------------------------------------
// maxp: per (b,z,tt): num[t,s,l] GEMM with register tiles, fused max over s.
// ---------------------------------------------------------------------------
__global__ __launch_bounds__(128) void maxp_kernel(
    const float* __restrict__ hs_fw, const float* __restrict__ hs_bw,
    const float* __restrict__ mp_W, const float* __restrict__ nm4,
    float* __restrict__ m_out)
{
  const int b = blockIdx.x, z = blockIdx.y, tt = blockIdx.z;
  const int dir = z & 1;
  const float* HS = dir ? hs_bw : hs_fw;
  const int p_n = (z < 2) ? b : 128 + b;
  const int h_n = (z < 2) ? 128 + b : b;
  const int t_base = tt * 8;
  const float* Wm = mp_W + dir * 24000 + 6000;

  __shared__ float psh[8 * 100];
  __shared__ float hsh[64 * 100];
  __shared__ float wsh[20 * 100];

  const int tid = threadIdx.x;
  const int t_loc = tid >> 4;
  const int sg = (tid >> 1) & 7;
  const int lg = tid & 1;
  const int t = t_base + t_loc;

  float acc[8][10];
#pragma unroll
  for (int i = 0; i < 8; i++)
#pragma unroll
    for (int j = 0; j < 10; j++) acc[i][j] = 0.f;

  for (int kc = 0; kc < 300; kc += 100) {
    for (int e = tid; e < 200; e += 128) {
      int row = e / 25, q = e - row * 25;
      float4 v = *(const float4*)(HS + ((size_t)(t_base + row) * 256 + p_n) * 300 + kc + q * 4);
      *(float4*)&psh[row * 100 + q * 4] = v;
    }
    for (int e = tid; e < 1600; e += 128) {
      int row = e / 25, q = e - row * 25;
      float4 v = *(const float4*)(HS + ((size_t)row * 256 + h_n) * 300 + kc + q * 4);
      *(float4*)&hsh[row * 100 + q * 4] = v;
    }
    for (int e = tid; e < 500; e += 128) {
      int row = e / 25, q = e - row * 25;
      float4 w = *(const float4*)(Wm + (size_t)row * 300 + kc + q * 4);
      w.x *= w.x; w.y *= w.y; w.z *= w.z; w.w *= w.w;
      *(float4*)&wsh[row * 100 + q * 4] = w;
    }
    __syncthreads();
    for (int kq = 0; kq < 25; kq++) {
      float4 pv = *(const float4*)&psh[t_loc * 100 + kq * 4];
      float4 hv[8];
#pragma unroll
      for (int i = 0; i < 8; i++) hv[i] = *(const float4*)&hsh[(sg + 8 * i) * 100 + kq * 4];
#pragma unroll
      for (int j = 0; j < 10; j++) {
        float4 wv = *(const float4*)&wsh[(lg * 10 + j) * 100 + kq * 4];
        float pwx = pv.x * wv.x, pwy = pv.y * wv.y, pwz = pv.z * wv.z, pww = pv.w * wv.w;
#pragma unroll
        for (int i = 0; i < 8; i++)
          acc[i][j] += hv[i].x * pwx + hv[i].y * pwy + hv[i].z * pwz + hv[i].w * pww;
      }
    }
    __syncthreads();
  }

  const float* nmD = nm4 + ((size_t)dir * 4 + 1) * 327680;
  float pn[10], rmax[10];
#pragma unroll
  for (int j = 0; j < 10; j++) {
    pn[j] = nmD[((size_t)t * 256 + p_n) * 20 + lg * 10 + j];
    rmax[j] = -1e30f;
  }
#pragma unroll
  for (int i = 0; i < 8; i++) {
    int s = sg + 8 * i;
#pragma unroll
    for (int j = 0; j < 10; j++) {
      float hn = nmD[((size_t)s * 256 + h_n) * 20 + lg * 10 + j];
      float r = acc[i][j] / (pn[j] * hn + EPSF);
      rmax[j] = fmaxf(rmax[j], r);
    }
  }
#pragma unroll
  for (int off = 8; off >= 2; off >>= 1)
#pragma unroll
    for (int j = 0; j < 10; j++)
      rmax[j] = fmaxf(rmax[j], __shfl_down(rmax[j], off));
  if (sg == 0) {
    float* mrow = m_out + ((size_t)t * 128 + b) * 320 + z * 80;
#pragma unroll
    for (int j = 0; j < 10; j++) mrow[20 + lg * 10 + j] = rmax[j];
  }
}

// ---------------------------------------------------------------------------
// rest: per (b,z): full / attm / maxattm for all t. W^2 staged once in LDS.
// ---------------------------------------------------------------------------
__global__ __launch_bounds__(320) void rest_kernel(
    const float* __restrict__ hs_fw, const float* __restrict__ hs_bw,
    const float* __restrict__ mp_W, const float* __restrict__ nm4,
    const float* __restrict__ hmeanbuf, const int* __restrict__ idxbuf,
    float* __restrict__ m_out)
{
  const int b = blockIdx.x, z = blockIdx.y;
  const int dir = z & 1;
  const float* HS = dir ? hs_bw : hs_fw;
  const int p_n = (z < 2) ? b : 128 + b;
  const int h_n = (z < 2) ? 128 + b : b;
  const int v_t = dir ? 0 : 63;

  __shared__ float w2f[6000], w2a[6000], w2m[6000];
  __shared__ float vsh[300], psh[300], hmsh[300], hxsh[300];

  const int tid = threadIdx.x;
  const int g = tid >> 4, lane = tid & 15;
  const float* Wf = mp_W + dir * 24000;
  const float* Wa = Wf + 12000;
  const float* Wma = Wf + 18000;
  for (int e = tid; e < 6000; e += 320) {
    float a = Wf[e], bb = Wa[e], c = Wma[e];
    w2f[e] = a * a; w2a[e] = bb * bb; w2m[e] = c * c;
  }
  for (int e = tid; e < 300; e += 320)
    vsh[e] = HS[((size_t)v_t * 256 + h_n) * 300 + e];
  __syncthreads();

  const float* base0 = nm4 + ((size_t)dir * 4 + 0) * 327680;
  const float* base2 = nm4 + ((size_t)dir * 4 + 2) * 327680;
  const float* base3 = nm4 + ((size_t)dir * 4 + 3) * 327680;
  const float vnf = base0[((size_t)v_t * 256 + h_n) * 20 + g];

  for (int t = 0; t < 64; t++) {
    int idx = idxbuf[((size_t)z * 128 + b) * 64 + t];
    __syncthreads();
    for (int e = tid; e < 300; e += 320) {
      psh[e] = HS[((size_t)t * 256 + p_n) * 300 + e];
      hmsh[e] = hmeanbuf[(((size_t)z * 128 + b) * 64 + t) * 300 + e];
      hxsh[e] = HS[((size_t)idx * 256 + h_n) * 300 + e];
    }
    __syncthreads();
    float nf = 0.f, na = 0.f, qa = 0.f, nm = 0.f;
#pragma unroll
    for (int c = 0; c < 5; c++) {
      int k4 = lane + 16 * c;
      if (k4 < 75) {
        float4 p = *(const float4*)&psh[4 * k4];
        float4 v = *(const float4*)&vsh[4 * k4];
        float4 hm = *(const float4*)&hmsh[4 * k4];
        float4 hx = *(const float4*)&hxsh[4 * k4];
        float4 wf = *(const float4*)&w2f[g * 300 + 4 * k4];
        float4 wa = *(const float4*)&w2a[g * 300 + 4 * k4];
        float4 wm = *(const float4*)&w2m[g * 300 + 4 * k4];
        nf += p.x * v.x * wf.x + p.y * v.y * wf.y + p.z * v.z * wf.z + p.w * v.w * wf.w;
        na += p.x * hm.x * wa.x + p.y * hm.y * wa.y + p.z * hm.z * wa.z + p.w * hm.w * wa.w;
        qa += hm.x * hm.x * wa.x + hm.y * hm.y * wa.y + hm.z * hm.z * wa.z + hm.w * hm.w * wa.w;
        nm += p.x * hx.x * wm.x + p.y * hx.y * wm.y + p.z * hx.z * wm.z + p.w * hx.w * wm.w;
      }
    }
#pragma unroll
    for (int o = 8; o; o >>= 1) {
      nf += __shfl_down(nf, o);
      na += __shfl_down(na, o);
      qa += __shfl_down(qa, o);
      nm += __shfl_down(nm, o);
    }
    if (lane == 0) {
      float pnf = base0[((size_t)t * 256 + p_n) * 20 + g];
      float pna = base2[((size_t)t * 256 + p_n) * 20 + g];
      float pnm = base3[((size_t)t * 256 + p_n) * 20 + g];
      float qnm = base3[((size_t)idx * 256 + h_n) * 20 + g];
      float* mrow = m_out + ((size_t)t * 128 + b) * 320 + z * 80;
      mrow[g] = nf / (pnf * vnf + EPSF);
      mrow[40 + g] = na / (pna * sqrtf(qa) + EPSF);
      mrow[60 + g] = nm / (pnm * qnm + EPSF);
    }
  }
}

// ---------------------------------------------------------------------------
__global__ __launch_bounds__(256) void mlp_kernel(
    const float* __restrict__ shA0, const float* __restrict__ shA1,
    const float* __restrict__ bnG, const float* __restrict__ bnB,
    const float* __restrict__ W1, const float* __restrict__ b1,
    const float* __restrict__ W2, const float* __restrict__ b2,
    const float* __restrict__ outW, const float* __restrict__ outb,
    float* __restrict__ out)
{
  const int b = blockIdx.x;
  const int tid = threadIdx.x;
  __shared__ float x0[600], x1[600];
  const float inv = 1.0f / sqrtf(1.0f + 1e-5f);
  for (int j = tid; j < 600; j += 256) {
    float v = (j < 300) ? shA0[b * 300 + j] : shA1[b * 300 + (j - 300)];
    x0[j] = bnG[j] * v * inv + bnB[j];
  }
  __syncthreads();
  for (int j = tid; j < 600; j += 256) {
    float acc = b1[j];
    const float* w = W1 + (size_t)j * 600;
    for (int k = 0; k < 600; k++) acc += x0[k] * w[k];
    float r = fmaxf(acc, 0.f);
    x1[j] = bnG[600 + j] * r * inv + bnB[600 + j];
  }
  __syncthreads();
  for (int j = tid; j < 600; j += 256) {
    float acc = b2[j];
    const float* w = W2 + (size_t)j * 600;
    for (int k = 0; k < 600; k++) acc += x1[k] * w[k];
    float r = fmaxf(acc, 0.f);
    x0[j] = bnG[1200 + j] * r * inv + bnB[1200 + j];
  }
  __syncthreads();
  if (tid < 3) {
    float acc = outb[tid];
    const float* w = outW + tid * 600;
    for (int k = 0; k < 600; k++) acc += x0[k] * w[k];
    out[b * 3 + tid] = acc;
  }
}

// ---------------------------------------------------------------------------
extern "C" void kernel_launch(void* const* d_in, const int* in_sizes, int n_in,
                              void* d_out, int out_size, void* d_ws, size_t ws_size,
                              hipStream_t stream) {
  const int* premise = (const int*)d_in[0];
  const int* hypothesis = (const int*)d_in[1];
  const float* embW = (const float*)d_in[2];
  const float* cWih = (const float*)d_in[3];
  const float* cWhh = (const float*)d_in[4];
  const float* cb = (const float*)d_in[5];
  const float* mpW = (const float*)d_in[6];
  const float* aWihF = (const float*)d_in[7];
  const float* aWhhF = (const float*)d_in[8];
  const float* abF = (const float*)d_in[9];
  const float* aWihB = (const float*)d_in[10];
  const float* aWhhB = (const float*)d_in[11];
  const float* abB = (const float*)d_in[12];
  const float* bnG = (const float*)d_in[13];
  const float* bnB = (const float*)d_in[14];
  const float* W1 = (const float*)d_in[15];
  const float* b1 = (const float*)d_in[16];
  const float* W2 = (const float*)d_in[17];
  const float* b2 = (const float*)d_in[18];
  const float* outW = (const float*)d_in[19];
  const float* outb = (const float*)d_in[20];
  float* out = (float*)d_out;

  float* ws = (float*)d_ws;
  // workspace layout (floats)
  float* comb  = ws + 0;           // 4,915,200  (T,256,300); WhhT overlays after ctx-gates GEMM
  float* gates = ws + 4915200;     // 19,660,800 (T,256,1200); overlaid after ctx LSTM
  float* hsfw  = ws + 24576000;    // 4,915,200
  float* hsbw  = ws + 29491200;    // 4,915,200
  float* pnorm = ws + 34406400;    // 32,768    [2][64][256]
  float* mbuf  = ws + 35094528;    // 2,621,440 (T,128,320)
  float* sha   = ws + 38023168;    // 76,800    agg final h [2][128][300]

  // WhhT overlays in comb region (comb dead after ctx-gates GEMM)
  float* WTctx = comb;             // 360,000 (300,1200)
  float* WTaf  = comb + 360000;    // 360,000
  float* WTab  = comb + 720000;    // 360,000

  // overlays inside the dead ctx-gates region (valid between ctx LSTM and agg GEMMs)
  float* watt     = gates;                 // 2,097,152 [4][128][64][64]
  float* hmeanbuf = gates + 2097152;       // 9,830,400 [4][128][64][300]
  int*   idxbuf   = (int*)(gates + 11927552); // 32,768 [4][128][64]
  float* nm4      = gates + 11960320;      // 2,621,440 [2][4][64][256][20]

  // 1) embed
  embed_kernel<<<dim3(4800), dim3(256), 0, stream>>>(premise, hypothesis, embW, comb);

  // 2) ctx input gates (consumes comb)
  gemm_nt128<<<dim3(10, 128), dim3(256), 0, stream>>>(comb, cWih, cb, gates, 16384, 1200, 300);

  // 3) transpose recurrent weights into dead comb region
  transpose3_kernel<<<dim3(38, 10, 3), dim3(256), 0, stream>>>(
      cWhh, aWhhF, aWhhB, WTctx, WTaf, WTab);

  // 4) context LSTM: persistent, R=4, 128 blocks, XCD-partitioned dirs
  lstm_persist<4><<<dim3(128), dim3(960), 0, stream>>>(
      WTctx, WTctx, gates, gates, hsfw, hsbw, nullptr, 256);

  // 5) norms (all 4 W sets) + plain norms
  norm4_kernel<<<dim3(64, 256, 2), dim3(320), 0, stream>>>(hsfw, hsbw, mpW, nm4, pnorm);

  // 6) matching pipeline
  att_kernel<<<dim3(128, 4), dim3(256), 0, stream>>>(hsfw, hsbw, pnorm, watt, idxbuf);
  hmean_kernel<<<dim3(128, 4), dim3(256), 0, stream>>>(hsfw, hsbw, watt, hmeanbuf);
  maxp_kernel<<<dim3(128, 4, 8), dim3(128), 0, stream>>>(hsfw, hsbw, mpW, nm4, mbuf);
  rest_kernel<<<dim3(128, 4), dim3(320), 0, stream>>>(hsfw, hsbw, mpW, nm4, hmeanbuf, idxbuf, mbuf);

  // 7) agg input gates (overwrite gates region; overlays fully consumed)
  float* gaf = gates;
  float* gab = gates + 9830400;
  gemm_nt128<<<dim3(10, 64), dim3(256), 0, stream>>>(mbuf, aWihF, abF, gaf, 8192, 1200, 320);
  gemm_nt128<<<dim3(10, 64), dim3(256), 0, stream>>>(mbuf, aWihB, abB, gab, 8192, 1200, 320);

  // 8) aggregation LSTM: persistent, R=4, 64 blocks, XCD-partitioned dirs
  //    (XCDs 0-3 stream only WTaf, 4-7 only WTab -> per-XCD L2 working set 1.44 MB)
  lstm_persist<4><<<dim3(64), dim3(960), 0, stream>>>(
      WTaf, WTab, gaf, gab, nullptr, nullptr, sha, 128);

  // 9) MLP head
  mlp_kernel<<<dim3(128), dim3(256), 0, stream>>>(
      sha, sha + 38400, bnG, bnB, W1, b1, W2, b2, outW, outb, out);
}